// Round 9
// baseline (518.605 us; speedup 1.0000x reference)
//
#include <hip/hip_runtime.h>
#include <hip/hip_bf16.h>
#include <math.h>

typedef __attribute__((ext_vector_type(8))) short short8;
typedef __attribute__((ext_vector_type(4))) float f32x4;

#define MFMA_BF16 __builtin_amdgcn_mfma_f32_16x16x32_bf16

__device__ __forceinline__ ushort f2bf(float f) {
  union { __hip_bfloat16 h; ushort u; } c;
  c.h = __float2bfloat16(f);
  return c.u;
}
__device__ __forceinline__ void async_cp16(const ushort* g, ushort* l) {
  __builtin_amdgcn_global_load_lds(
      (const __attribute__((address_space(1))) void*)g,
      (__attribute__((address_space(3))) void*)l, 16, 0, 0);
}

// ------------- fused weight fp32->bf16 conversion + bias concat (one launch) -------------
__global__ __launch_bounds__(256) void conv_all(
    const float* __restrict__ Wq, const float* __restrict__ Wk,
    const float* __restrict__ Wv, const float* __restrict__ Wo,
    const float* __restrict__ W1, const float* __restrict__ W2,
    const float* __restrict__ bq, const float* __restrict__ bk,
    const float* __restrict__ bv,
    ushort* __restrict__ wqkv, ushort* __restrict__ wo,
    ushort* __restrict__ w1, ushort* __restrict__ w2,
    float* __restrict__ bqkv) {
  int i = blockIdx.x * 256 + threadIdx.x;   // float4 index
  if (i < 3145728) {
    const float* src; ushort* dst; int off;
    if (i < 786432)        { // Wq|Wk|Wv -> concatenated wqkv [3072,1024]
      dst = wqkv; off = i;
      if (i < 262144)      src = Wq + (size_t)i * 4;
      else if (i < 524288) src = Wk + (size_t)(i - 262144) * 4;
      else                 src = Wv + (size_t)(i - 524288) * 4;
    } else if (i < 1048576) { dst = wo; off = i - 786432;  src = Wo + (size_t)off * 4; }
    else if (i < 2097152)   { dst = w1; off = i - 1048576; src = W1 + (size_t)off * 4; }
    else                    { dst = w2; off = i - 2097152; src = W2 + (size_t)off * 4; }
    float4 v = *(const float4*)src;
    ushort4 o;
    o.x = f2bf(v.x); o.y = f2bf(v.y); o.z = f2bf(v.z); o.w = f2bf(v.w);
    ((ushort4*)dst)[off] = o;
  } else if (i < 3146496) {  // biases: 3 x 256 float4
    int off = i - 3145728;
    const float* src;
    if (off < 256)      src = bq + (size_t)off * 4;
    else if (off < 512) src = bk + (size_t)(off - 256) * 4;
    else                src = bv + (size_t)(off - 512) * 4;
    ((float4*)bqkv)[off] = *(const float4*)src;
  }
}

// ---------------- layernorm: one block per 1024-float row -> bf16 ----------------
__global__ __launch_bounds__(256) void ln_kernel(const float* __restrict__ x,
    const float* __restrict__ g, const float* __restrict__ b,
    ushort* __restrict__ out) {
  const int row = blockIdx.x, t = threadIdx.x;
  float4 v = ((const float4*)(x + (size_t)row * 1024))[t];
  float s  = v.x + v.y + v.z + v.w;
  float ss = v.x*v.x + v.y*v.y + v.z*v.z + v.w*v.w;
  #pragma unroll
  for (int off = 32; off >= 1; off >>= 1) {
    s  += __shfl_xor(s, off);
    ss += __shfl_xor(ss, off);
  }
  __shared__ float red[8];
  int wv = t >> 6, ln = t & 63;
  if (ln == 0) { red[wv] = s; red[4 + wv] = ss; }
  __syncthreads();
  float S  = red[0] + red[1] + red[2] + red[3];
  float SS = red[4] + red[5] + red[6] + red[7];
  float mu  = S * (1.0f/1024.0f);
  float var = SS * (1.0f/1024.0f) - mu*mu;
  float rs  = rsqrtf(var + 1e-6f);
  float4 gv = ((const float4*)g)[t];
  float4 bv = ((const float4*)b)[t];
  ushort4 o;
  o.x = f2bf((v.x-mu)*rs*gv.x + bv.x);
  o.y = f2bf((v.y-mu)*rs*gv.y + bv.y);
  o.z = f2bf((v.z-mu)*rs*gv.z + bv.z);
  o.w = f2bf((v.w-mu)*rs*gv.w + bv.w);
  ((ushort4*)(out + (size_t)row*1024))[t] = o;
}

enum { EPI_QK = 0, EPI_VT = 1, EPI_WO = 2, EPI_GELU = 3, EPI_OUT = 4 };

// ------- 256x256 bf16 GEMM, BK=64, 8 waves, 4-phase pipeline (R8 schedule) -------
// R8's proven schedule + ledger, with REGISTER-HOISTED fragments: af0 read @ph0,
// af1 @ph1 (held through ph2/ph3); bf read @ph0 (B0) and @ph2 (B1, same regs).
// ds_read_b128 per tile/wave: 40 -> 24. Stage order A0,B0,A1,B1; vmcnt(4) covers
// the next phase's reads (see R8 ledger); tail 2/0/0/0.
template <int EPI>
__global__ __launch_bounds__(512, 2) void gemm256_kernel(const ushort* __restrict__ A,
    const ushort* __restrict__ Bw, const float* __restrict__ bias,
    void* __restrict__ outp, void* __restrict__ outp2, int K, int N, float scale) {
  __shared__ ushort As[2][256 * 64];   // 32 KB per buf
  __shared__ ushort Bs[2][256 * 64];
  const int t = threadIdx.x;
  const int lane = t & 63, wave = t >> 6;
  const int col = lane & 15, quad = lane >> 4;
  const int m0 = blockIdx.x * 256, n0 = blockIdx.y * 256;
  const int wm = wave >> 2, wn = wave & 3;   // 2 x 4

  f32x4 acc[8][4];
  #pragma unroll
  for (int i = 0; i < 8; i++)
    #pragma unroll
    for (int j = 0; j < 4; j++)
      acc[i][j] = (f32x4){0.f, 0.f, 0.f, 0.f};

  size_t aoff[2], boff[2];
  int d0[2];
  #pragma unroll
  for (int i = 0; i < 2; i++) {
    int c = i * 512 + t, r = c >> 3, p = c & 7;
    aoff[i] = (size_t)(m0 + r) * K + (p ^ (r & 7)) * 8;
    boff[i] = (size_t)(n0 + r) * K + (p ^ (r & 7)) * 8;
    d0[i] = c * 8;
  }
  const size_t up = (size_t)128 * K;

  const int NT = K >> 6;
  // prologue: tile 0, order A0,B0,A1,B1; wait A0,B0 (A1,B1 in flight)
  #pragma unroll
  for (int i = 0; i < 2; i++) async_cp16(A  + aoff[i],      &As[0][d0[i]]);
  #pragma unroll
  for (int i = 0; i < 2; i++) async_cp16(Bw + boff[i],      &Bs[0][d0[i]]);
  #pragma unroll
  for (int i = 0; i < 2; i++) async_cp16(A  + aoff[i] + up, &As[0][8192 + d0[i]]);
  #pragma unroll
  for (int i = 0; i < 2; i++) async_cp16(Bw + boff[i] + up, &Bs[0][8192 + d0[i]]);
  asm volatile("s_waitcnt vmcnt(4)" ::: "memory");
  __builtin_amdgcn_sched_barrier(0);
  __builtin_amdgcn_s_barrier();
  __builtin_amdgcn_sched_barrier(0);

  short8 af0[4][2], af1[4][2], bf[2][2];
  for (int kt = 0; kt < NT; kt++) {
    const int cur = kt & 1, nxt = cur ^ 1;
    const size_t ko = (size_t)(kt + 1) << 6;
    const bool more = (kt + 1 < NT);

    // ---- ph0 (ha=0, hb=0): read af0 + bf(B0); stage A0(t+1)
    #pragma unroll
    for (int tml = 0; tml < 4; tml++) {
      const int row = wm * 64 + tml * 16 + col;
      #pragma unroll
      for (int c = 0; c < 2; c++)
        af0[tml][c] = *(const short8*)&As[cur][row * 64 + (((c * 4 + quad) ^ (row & 7)) * 8)];
    }
    #pragma unroll
    for (int tnl = 0; tnl < 2; tnl++) {
      const int row = wn * 32 + tnl * 16 + col;
      #pragma unroll
      for (int c = 0; c < 2; c++)
        bf[tnl][c] = *(const short8*)&Bs[cur][row * 64 + (((c * 4 + quad) ^ (row & 7)) * 8)];
    }
    if (more) {
      #pragma unroll
      for (int i = 0; i < 2; i++) async_cp16(A + aoff[i] + ko, &As[nxt][d0[i]]);
      asm volatile("s_waitcnt vmcnt(4)" ::: "memory");
    } else {
      asm volatile("s_waitcnt vmcnt(2)" ::: "memory");
    }
    __builtin_amdgcn_sched_barrier(0);
    __builtin_amdgcn_s_barrier();
    asm volatile("s_waitcnt lgkmcnt(0)" ::: "memory");
    __builtin_amdgcn_sched_barrier(0);
    __builtin_amdgcn_s_setprio(1);
    #pragma unroll
    for (int tml = 0; tml < 4; tml++)
      #pragma unroll
      for (int tnl = 0; tnl < 2; tnl++) {
        acc[tml][tnl] = MFMA_BF16(af0[tml][0], bf[tnl][0], acc[tml][tnl], 0, 0, 0);
        acc[tml][tnl] = MFMA_BF16(af0[tml][1], bf[tnl][1], acc[tml][tnl], 0, 0, 0);
      }
    __builtin_amdgcn_s_setprio(0);
    __builtin_amdgcn_sched_barrier(0);
    __builtin_amdgcn_s_barrier();
    __builtin_amdgcn_sched_barrier(0);

    // ---- ph1 (ha=1, hb=0): read af1; stage B0(t+1)
    #pragma unroll
    for (int tml = 0; tml < 4; tml++) {
      const int row = 128 + wm * 64 + tml * 16 + col;
      #pragma unroll
      for (int c = 0; c < 2; c++)
        af1[tml][c] = *(const short8*)&As[cur][row * 64 + (((c * 4 + quad) ^ (row & 7)) * 8)];
    }
    if (more) {
      #pragma unroll
      for (int i = 0; i < 2; i++) async_cp16(Bw + boff[i] + ko, &Bs[nxt][d0[i]]);
      asm volatile("s_waitcnt vmcnt(4)" ::: "memory");
    } else {
      asm volatile("s_waitcnt vmcnt(0)" ::: "memory");
    }
    __builtin_amdgcn_sched_barrier(0);
    __builtin_amdgcn_s_barrier();
    asm volatile("s_waitcnt lgkmcnt(0)" ::: "memory");
    __builtin_amdgcn_sched_barrier(0);
    __builtin_amdgcn_s_setprio(1);
    #pragma unroll
    for (int tml = 0; tml < 4; tml++)
      #pragma unroll
      for (int tnl = 0; tnl < 2; tnl++) {
        acc[4+tml][tnl] = MFMA_BF16(af1[tml][0], bf[tnl][0], acc[4+tml][tnl], 0, 0, 0);
        acc[4+tml][tnl] = MFMA_BF16(af1[tml][1], bf[tnl][1], acc[4+tml][tnl], 0, 0, 0);
      }
    __builtin_amdgcn_s_setprio(0);
    __builtin_amdgcn_sched_barrier(0);
    __builtin_amdgcn_s_barrier();
    __builtin_amdgcn_sched_barrier(0);

    // ---- ph2 (ha=0, hb=1): read bf(B1) (overwrite); stage A1(t+1)
    #pragma unroll
    for (int tnl = 0; tnl < 2; tnl++) {
      const int row = 128 + wn * 32 + tnl * 16 + col;
      #pragma unroll
      for (int c = 0; c < 2; c++)
        bf[tnl][c] = *(const short8*)&Bs[cur][row * 64 + (((c * 4 + quad) ^ (row & 7)) * 8)];
    }
    if (more) {
      #pragma unroll
      for (int i = 0; i < 2; i++) async_cp16(A + aoff[i] + up + ko, &As[nxt][8192 + d0[i]]);
      asm volatile("s_waitcnt vmcnt(4)" ::: "memory");
    } else {
      asm volatile("s_waitcnt vmcnt(0)" ::: "memory");
    }
    __builtin_amdgcn_sched_barrier(0);
    __builtin_amdgcn_s_barrier();
    asm volatile("s_waitcnt lgkmcnt(0)" ::: "memory");
    __builtin_amdgcn_sched_barrier(0);
    __builtin_amdgcn_s_setprio(1);
    #pragma unroll
    for (int tml = 0; tml < 4; tml++)
      #pragma unroll
      for (int tnl = 0; tnl < 2; tnl++) {
        acc[tml][2+tnl] = MFMA_BF16(af0[tml][0], bf[tnl][0], acc[tml][2+tnl], 0, 0, 0);
        acc[tml][2+tnl] = MFMA_BF16(af0[tml][1], bf[tnl][1], acc[tml][2+tnl], 0, 0, 0);
      }
    __builtin_amdgcn_s_setprio(0);
    __builtin_amdgcn_sched_barrier(0);
    __builtin_amdgcn_s_barrier();
    __builtin_amdgcn_sched_barrier(0);

    // ---- ph3 (ha=1, hb=1): no reads; stage B1(t+1)
    if (more) {
      #pragma unroll
      for (int i = 0; i < 2; i++) async_cp16(Bw + boff[i] + up + ko, &Bs[nxt][8192 + d0[i]]);
      asm volatile("s_waitcnt vmcnt(4)" ::: "memory");
    } else {
      asm volatile("s_waitcnt vmcnt(0)" ::: "memory");
    }
    __builtin_amdgcn_sched_barrier(0);
    __builtin_amdgcn_s_barrier();
    asm volatile("s_waitcnt lgkmcnt(0)" ::: "memory");
    __builtin_amdgcn_sched_barrier(0);
    __builtin_amdgcn_s_setprio(1);
    #pragma unroll
    for (int tml = 0; tml < 4; tml++)
      #pragma unroll
      for (int tnl = 0; tnl < 2; tnl++) {
        acc[4+tml][2+tnl] = MFMA_BF16(af1[tml][0], bf[tnl][0], acc[4+tml][2+tnl], 0, 0, 0);
        acc[4+tml][2+tnl] = MFMA_BF16(af1[tml][1], bf[tnl][1], acc[4+tml][2+tnl], 0, 0, 0);
      }
    __builtin_amdgcn_s_setprio(0);
    __builtin_amdgcn_sched_barrier(0);
    __builtin_amdgcn_s_barrier();
    __builtin_amdgcn_sched_barrier(0);
  }

  #pragma unroll
  for (int tm = 0; tm < 8; tm++) {
    const int ha = tm >> 2, tml = tm & 3;
    #pragma unroll
    for (int tn = 0; tn < 4; tn++) {
      const int hb = tn >> 1, tnl = tn & 1;
      const int n = n0 + hb * 128 + wn * 32 + tnl * 16 + col;
      const float bn = bias[n];
      #pragma unroll
      for (int r = 0; r < 4; r++) {
        const int m = m0 + ha * 128 + wm * 64 + tml * 16 + quad * 4 + r;
        float v = acc[tm][tn][r] + bn;
        if (EPI == EPI_QK) {
          int nl = n & 1023, h = nl >> 6, hd = nl & 63;
          int bb = m >> 11, s2 = m & 2047;
          if (n < 1024)
            ((ushort*)outp)[(((size_t)(bb * 16 + h) * 2048 + s2) * 64) + hd] = f2bf(v * scale);
          else
            ((ushort*)outp2)[(((size_t)(bb * 16 + h) * 2048 + s2) * 64) + hd] = f2bf(v);
        } else {  // EPI_GELU
          float u = v * 0.7978845608028654f * (1.0f + 0.044715f * v * v);
          float e = __builtin_amdgcn_exp2f(u * 2.885390081777927f);  // e^{2u}
          float th = 1.0f - 2.0f * __builtin_amdgcn_rcpf(e + 1.0f);
          ((ushort*)outp)[(size_t)m * N + n] = f2bf(0.5f * v * (1.0f + th));
        }
      }
    }
  }
}

// ------- 256x128 bf16 GEMM, BK=64, 8 waves, 4-phase pipeline (VT / WO / OUT) -------
// Units: A0 (rows 0-127, 2 loads/thr), B0 (n 0-63, 1), A1 (2), B1 (n 64-127, 1);
// staged at phases 0,1,2,3. Reads: ph0 af0+bf(B0); ph1 af1; ph2 bf(B1); ph3 none.
// Per-load ledger (steady): waits vmcnt(3)/3/5/3 — each covers exactly the next
// phase's ds_reads (A0(t+1)+B0(t+1)... details in session journal); tail 1/0/0/0.
// Grid exactly 256 blocks (1/CU) for all three shapes. Same row&7 chunk-XOR swizzle.
template <int EPI>
__global__ __launch_bounds__(512, 2) void gemmW_kernel(const ushort* __restrict__ A,
    const ushort* __restrict__ Bw, const float* __restrict__ bias,
    const float* __restrict__ res, void* __restrict__ outp, int K, int N) {
  __shared__ ushort As[2][256 * 64];   // 32 KB per buf
  __shared__ ushort Bs[2][128 * 64];   // 16 KB per buf
  const int t = threadIdx.x;
  const int lane = t & 63, wave = t >> 6;
  const int col = lane & 15, quad = lane >> 4;
  const int m0 = blockIdx.x * 256, n0 = blockIdx.y * 128;
  const int wm = wave >> 1, wn = wave & 1;   // 4 x 2

  f32x4 acc[4][4];
  #pragma unroll
  for (int i = 0; i < 4; i++)
    #pragma unroll
    for (int j = 0; j < 4; j++)
      acc[i][j] = (f32x4){0.f, 0.f, 0.f, 0.f};

  size_t aoff[2];
  int ad0[2];
  #pragma unroll
  for (int i = 0; i < 2; i++) {
    int c = i * 512 + t, r = c >> 3, p = c & 7;
    aoff[i] = (size_t)(m0 + r) * K + (p ^ (r & 7)) * 8;
    ad0[i] = c * 8;
  }
  size_t boff;
  int bd0;
  {
    int c = t, r = c >> 3, p = c & 7;   // r in 0..63 (one B unit = 64 n-rows)
    boff = (size_t)(n0 + r) * K + (p ^ (r & 7)) * 8;
    bd0 = c * 8;
  }
  const size_t upA = (size_t)128 * K;
  const size_t upB = (size_t)64 * K;

  const int NT = K >> 6;
  // prologue: A0,B0,A1,B1 of tile 0 (6 loads); wait A0,B0 (leave A1+B1 = 3)
  #pragma unroll
  for (int i = 0; i < 2; i++) async_cp16(A + aoff[i], &As[0][ad0[i]]);
  async_cp16(Bw + boff, &Bs[0][bd0]);
  #pragma unroll
  for (int i = 0; i < 2; i++) async_cp16(A + aoff[i] + upA, &As[0][8192 + ad0[i]]);
  async_cp16(Bw + boff + upB, &Bs[0][4096 + bd0]);
  asm volatile("s_waitcnt vmcnt(3)" ::: "memory");
  __builtin_amdgcn_sched_barrier(0);
  __builtin_amdgcn_s_barrier();
  __builtin_amdgcn_sched_barrier(0);

  short8 af0[2][2], af1[2][2], bf[2][2];
  for (int kt = 0; kt < NT; kt++) {
    const int cur = kt & 1, nxt = cur ^ 1;
    const size_t ko = (size_t)(kt + 1) << 6;
    const bool more = (kt + 1 < NT);

    // ---- ph0 (ha=0, hb=0): read af0 + bf(B0); stage A0(t+1); wait covers A1(t)
    #pragma unroll
    for (int tml = 0; tml < 2; tml++) {
      const int row = wm * 32 + tml * 16 + col;
      #pragma unroll
      for (int c = 0; c < 2; c++)
        af0[tml][c] = *(const short8*)&As[cur][row * 64 + (((c * 4 + quad) ^ (row & 7)) * 8)];
    }
    #pragma unroll
    for (int tnl = 0; tnl < 2; tnl++) {
      const int row = wn * 32 + tnl * 16 + col;
      #pragma unroll
      for (int c = 0; c < 2; c++)
        bf[tnl][c] = *(const short8*)&Bs[cur][row * 64 + (((c * 4 + quad) ^ (row & 7)) * 8)];
    }
    if (more) {
      #pragma unroll
      for (int i = 0; i < 2; i++) async_cp16(A + aoff[i] + ko, &As[nxt][ad0[i]]);
      asm volatile("s_waitcnt vmcnt(3)" ::: "memory");
    } else {
      asm volatile("s_waitcnt vmcnt(1)" ::: "memory");
    }
    __builtin_amdgcn_sched_barrier(0);
    __builtin_amdgcn_s_barrier();
    asm volatile("s_waitcnt lgkmcnt(0)" ::: "memory");
    __builtin_amdgcn_sched_barrier(0);
    __builtin_amdgcn_s_setprio(1);
    #pragma unroll
    for (int tml = 0; tml < 2; tml++)
      #pragma unroll
      for (int tnl = 0; tnl < 2; tnl++) {
        acc[tml][tnl] = MFMA_BF16(af0[tml][0], bf[tnl][0], acc[tml][tnl], 0, 0, 0);
        acc[tml][tnl] = MFMA_BF16(af0[tml][1], bf[tnl][1], acc[tml][tnl], 0, 0, 0);
      }
    __builtin_amdgcn_s_setprio(0);
    __builtin_amdgcn_sched_barrier(0);
    __builtin_amdgcn_s_barrier();
    __builtin_amdgcn_sched_barrier(0);

    // ---- ph1 (ha=1, hb=0): read af1; stage B0(t+1); wait covers B1(t)
    #pragma unroll
    for (int tml = 0; tml < 2; tml++) {
      const int row = 128 + wm * 32 + tml * 16 + col;
      #pragma unroll
      for (int c = 0; c < 2; c++)
        af1[tml][c] = *(const short8*)&As[cur][row * 64 + (((c * 4 + quad) ^ (row & 7)) * 8)];
    }
    if (more) {
      async_cp16(Bw + boff + ko, &Bs[nxt][bd0]);
      asm volatile("s_waitcnt vmcnt(3)" ::: "memory");
    } else {
      asm volatile("s_waitcnt vmcnt(0)" ::: "memory");
    }
    __builtin_amdgcn_sched_barrier(0);
    __builtin_amdgcn_s_barrier();
    asm volatile("s_waitcnt lgkmcnt(0)" ::: "memory");
    __builtin_amdgcn_sched_barrier(0);
    __builtin_amdgcn_s_setprio(1);
    #pragma unroll
    for (int tml = 0; tml < 2; tml++)
      #pragma unroll
      for (int tnl = 0; tnl < 2; tnl++) {
        acc[2+tml][tnl] = MFMA_BF16(af1[tml][0], bf[tnl][0], acc[2+tml][tnl], 0, 0, 0);
        acc[2+tml][tnl] = MFMA_BF16(af1[tml][1], bf[tnl][1], acc[2+tml][tnl], 0, 0, 0);
      }
    __builtin_amdgcn_s_setprio(0);
    __builtin_amdgcn_sched_barrier(0);
    __builtin_amdgcn_s_barrier();
    __builtin_amdgcn_sched_barrier(0);

    // ---- ph2 (ha=0, hb=1): read bf(B1); stage A1(t+1); no wait needed (bounded)
    #pragma unroll
    for (int tnl = 0; tnl < 2; tnl++) {
      const int row = 64 + wn * 32 + tnl * 16 + col;
      #pragma unroll
      for (int c = 0; c < 2; c++)
        bf[tnl][c] = *(const short8*)&Bs[cur][4096 + ((row - 64) * 64) + (((c * 4 + quad) ^ (row & 7)) * 8)];
    }
    if (more) {
      #pragma unroll
      for (int i = 0; i < 2; i++) async_cp16(A + aoff[i] + upA + ko, &As[nxt][8192 + ad0[i]]);
      asm volatile("s_waitcnt vmcnt(5)" ::: "memory");
    } else {
      asm volatile("s_waitcnt vmcnt(0)" ::: "memory");
    }
    __builtin_amdgcn_sched_barrier(0);
    __builtin_amdgcn_s_barrier();
    asm volatile("s_waitcnt lgkmcnt(0)" ::: "memory");
    __builtin_amdgcn_sched_barrier(0);
    __builtin_amdgcn_s_setprio(1);
    #pragma unroll
    for (int tml = 0; tml < 2; tml++)
      #pragma unroll
      for (int tnl = 0; tnl < 2; tnl++) {
        acc[tml][2+tnl] = MFMA_BF16(af0[tml][0], bf[tnl][0], acc[tml][2+tnl], 0, 0, 0);
        acc[tml][2+tnl] = MFMA_BF16(af0[tml][1], bf[tnl][1], acc[tml][2+tnl], 0, 0, 0);
      }
    __builtin_amdgcn_s_setprio(0);
    __builtin_amdgcn_sched_barrier(0);
    __builtin_amdgcn_s_barrier();
    __builtin_amdgcn_sched_barrier(0);

    // ---- ph3 (ha=1, hb=1): no reads; stage B1(t+1); wait covers A0(t+1),B0(t+1)
    if (more) {
      async_cp16(Bw + boff + upB + ko, &Bs[nxt][4096 + bd0]);
      asm volatile("s_waitcnt vmcnt(3)" ::: "memory");
    } else {
      asm volatile("s_waitcnt vmcnt(0)" ::: "memory");
    }
    __builtin_amdgcn_sched_barrier(0);
    __builtin_amdgcn_s_barrier();
    asm volatile("s_waitcnt lgkmcnt(0)" ::: "memory");
    __builtin_amdgcn_sched_barrier(0);
    __builtin_amdgcn_s_setprio(1);
    #pragma unroll
    for (int tml = 0; tml < 2; tml++)
      #pragma unroll
      for (int tnl = 0; tnl < 2; tnl++) {
        acc[2+tml][2+tnl] = MFMA_BF16(af1[tml][0], bf[tnl][0], acc[2+tml][2+tnl], 0, 0, 0);
        acc[2+tml][2+tnl] = MFMA_BF16(af1[tml][1], bf[tnl][1], acc[2+tml][2+tnl], 0, 0, 0);
      }
    __builtin_amdgcn_s_setprio(0);
    __builtin_amdgcn_sched_barrier(0);
    __builtin_amdgcn_s_barrier();
    __builtin_amdgcn_sched_barrier(0);
  }

  #pragma unroll
  for (int tm = 0; tm < 4; tm++) {
    const int ha = tm >> 1, tml = tm & 1;
    #pragma unroll
    for (int tn = 0; tn < 4; tn++) {
      const int hb = tn >> 1, tnl = tn & 1;
      const int n = n0 + hb * 64 + wn * 32 + tnl * 16 + col;
      #pragma unroll
      for (int r = 0; r < 4; r++) {
        const int m = m0 + ha * 128 + wm * 32 + tml * 16 + quad * 4 + r;
        float v = acc[tm][tn][r];
        if (EPI == EPI_VT) {
          // A=Wv (m = v-dim), Bw=xn (n = token); bias indexed by m
          float vv = v + bias[m];
          int h = m >> 6, hd = m & 63, bb = n >> 11, s2 = n & 2047;
          ((ushort*)outp)[((size_t)((bb * 16 + h) * 64 + hd)) * 2048 + s2] = f2bf(vv);
        } else {  // EPI_WO / EPI_OUT: float out + bias + residual
          ((float*)outp)[(size_t)m * N + n] = v + bias[n] + res[(size_t)m * N + n];
        }
      }
    }
  }
}

// ---------------- flash attention v13: v11 + l-sum via ones-MFMA ----------
// l = sum_k P[k][q] computed by one extra MFMA per (c,qg) with A = all-ones
// fragment: C[r][q] = sum_k B[k][q], identical in all rows/lanes -> no final
// cross-lane reduce. Removes 32 VALU adds/iter from the busier pipe.
__global__ __launch_bounds__(256) void attn_kernel(const ushort* __restrict__ Qb,
    const ushort* __restrict__ Kb, const ushort* __restrict__ Vt,
    ushort* __restrict__ ctx) {
  const int lane = threadIdx.x & 63, wave = threadIdx.x >> 6;
  const int col = lane & 15, quad = lane >> 4;
  const int bx = blockIdx.x;
  const int bh = bx & 63;          // XCD = bh % 8 for every q-tile of this head
  const int qt = bx >> 6;          // 0..15
  const int qbase = qt * 128 + wave * 32;
  const ushort* Qh = Qb + (size_t)bh * 2048 * 64;
  const ushort* Kh = Kb + (size_t)bh * 2048 * 64;
  const ushort* Vh = Vt + (size_t)bh * 64 * 2048;

  short8 qa[2][2];
  #pragma unroll
  for (int qg = 0; qg < 2; qg++) {
    const ushort* Qr = Qh + (size_t)(qbase + qg * 16 + col) * 64 + quad * 8;
    qa[qg][0] = *(const short8*)Qr;
    qa[qg][1] = *(const short8*)(Qr + 32);
  }

  short8 ones8;
  #pragma unroll
  for (int i = 0; i < 8; i++) ones8[i] = (short)0x3F80;   // 1.0 bf16

  f32x4 Ot[2][4], Ol[2];
  #pragma unroll
  for (int qg = 0; qg < 2; qg++) {
    Ol[qg] = (f32x4){0.f, 0.f, 0.f, 0.f};
    #pragma unroll
    for (int dt = 0; dt < 4; dt++) Ot[qg][dt] = (f32x4){0.f, 0.f, 0.f, 0.f};
  }

  __shared__ ushort Ks[2][2][64 * 32];   // [buf][d-half][key*32 + swz-chunk] 16 KB
  __shared__ ushort Vs[2][2][64 * 32];   // [buf][key-half][d*32 + swz-chunk] 16 KB
  __shared__ ushort P_lds[4][16][64];    // [wave][q][8 x 16B chunks, swz] 8 KB

  const int lrow = lane >> 2;
  const int srow = wave * 16 + lrow;                       // row this lane stages
  const int lcol = ((lane & 3) ^ ((srow >> 1) & 3)) * 8;   // swizzled 16B chunk in 64B half
  const ushort* Kg = Kh + (size_t)srow * 64 + lcol;        // + kb*64 (+32 for half 1)
  const ushort* Vg = Vh + (size_t)srow * 2048 + lcol;      // + kb   (+32 for half 1)
  const int so = (wave * 16) * 32;

  const int kvswz = (col >> 1) & 3;   // fragment-read XOR (rows kt*16+col: (row>>1)&3)
  const int pswz = col & 7;           // P chunk XOR

  // prologue: stage chunk 0 into buf 0
  async_cp16(Kg,      &Ks[0][0][so]);
  async_cp16(Kg + 32, &Ks[0][1][so]);
  async_cp16(Vg,      &Vs[0][0][so]);
  async_cp16(Vg + 32, &Vs[0][1][so]);
  __syncthreads();

  int cur = 0;
  for (int kb = 0; kb < 2048; kb += 64) {
    if (kb + 64 < 2048) {
      const int nxt = cur ^ 1;
      async_cp16(Kg + (size_t)(kb + 64) * 64,      &Ks[nxt][0][so]);
      async_cp16(Kg + (size_t)(kb + 64) * 64 + 32, &Ks[nxt][1][so]);
      async_cp16(Vg + (kb + 64),                   &Vs[nxt][0][so]);
      async_cp16(Vg + (kb + 64) + 32,              &Vs[nxt][1][so]);
    }

    // fragments from LDS (shared across the 2 q-groups), swizzled reads
    short8 kf[4][2], vf[4][2];
    #pragma unroll
    for (int kt = 0; kt < 4; kt++)
      #pragma unroll
      for (int c = 0; c < 2; c++)
        kf[kt][c] = *(const short8*)&Ks[cur][c][(kt * 16 + col) * 32 + (quad ^ kvswz) * 8];
    #pragma unroll
    for (int dt = 0; dt < 4; dt++)
      #pragma unroll
      for (int c = 0; c < 2; c++)
        vf[dt][c] = *(const short8*)&Vs[cur][c][(dt * 16 + col) * 32 + (quad ^ kvswz) * 8];

    #pragma unroll
    for (int qg = 0; qg < 2; qg++) {
      f32x4 s[4];
      __builtin_amdgcn_s_setprio(1);
      #pragma unroll
      for (int kt = 0; kt < 4; kt++) {
        s[kt] = (f32x4){0.f, 0.f, 0.f, 0.f};
        s[kt] = MFMA_BF16(kf[kt][0], qa[qg][0], s[kt], 0, 0, 0);
        s[kt] = MFMA_BF16(kf[kt][1], qa[qg][1], s[kt], 0, 0, 0);
      }
      __builtin_amdgcn_s_setprio(0);
      ushort(*P)[64] = P_lds[wave];
      #pragma unroll
      for (int kt = 0; kt < 4; kt++) {
        float p0 = __builtin_amdgcn_exp2f(s[kt][0]);
        float p1 = __builtin_amdgcn_exp2f(s[kt][1]);
        float p2 = __builtin_amdgcn_exp2f(s[kt][2]);
        float p3 = __builtin_amdgcn_exp2f(s[kt][3]);
        uint2 pk;
        asm("v_cvt_pk_bf16_f32 %0, %1, %2" : "=v"(pk.x) : "v"(p0), "v"(p1));
        asm("v_cvt_pk_bf16_f32 %0, %1, %2" : "=v"(pk.y) : "v"(p2), "v"(p3));
        *(uint2*)&P[col][(((2 * kt + (quad >> 1)) ^ pswz) * 8) + (quad & 1) * 4] = pk;
      }
      // PV for this qg (same-wave LDS RAW handled in-order; no barrier needed)
      #pragma unroll
      for (int c = 0; c < 2; c++) {
        short8 pf = *(const short8*)&P_lds[wave][col][((4 * c + quad) ^ pswz) * 8];
        __builtin_amdgcn_s_setprio(1);
        #pragma unroll
        for (int dt = 0; dt < 4; dt++)
          Ot[qg][dt] = MFMA_BF16(vf[dt][c], pf, Ot[qg][dt], 0, 0, 0);
        Ol[qg] = MFMA_BF16(ones8, pf, Ol[qg], 0, 0, 0);   // l-sum on MFMA pipe
        __builtin_amdgcn_s_setprio(0);
      }
    }
    __syncthreads();
    cur ^= 1;
  }

  const int bb = bh >> 4, h = bh & 15;
  #pragma unroll
  for (int qg = 0; qg < 2; qg++) {
    float inv = __builtin_amdgcn_rcpf(Ol[qg][0]);   // identical in all lanes/regs
    const int q = qbase + qg * 16 + col;
    size_t base = ((size_t)(bb * 2048 + q)) * 1024 + h * 64;
    #pragma unroll
    for (int dt = 0; dt < 4; dt++) {
      ushort4 o;
      o.x = f2bf(Ot[qg][dt][0] * inv);
      o.y = f2bf(Ot[qg][dt][1] * inv);
      o.z = f2bf(Ot[qg][dt][2] * inv);
      o.w = f2bf(Ot[qg][dt][3] * inv);
      *(ushort4*)&ctx[base + dt * 16 + quad * 4] = o;
    }
  }
}

// ---------------- host ----------------
extern "C" void kernel_launch(void* const* d_in, const int* in_sizes, int n_in,
                              void* d_out, int out_size, void* d_ws, size_t ws_size,
                              hipStream_t stream) {
  const float* x     = (const float*)d_in[0];
  const float* Wq    = (const float*)d_in[1];
  const float* bq    = (const float*)d_in[2];
  const float* Wk    = (const float*)d_in[3];
  const float* bk    = (const float*)d_in[4];
  const float* Wv    = (const float*)d_in[5];
  const float* bv    = (const float*)d_in[6];
  const float* Wo    = (const float*)d_in[7];
  const float* bo    = (const float*)d_in[8];
  const float* W1    = (const float*)d_in[9];
  const float* b1    = (const float*)d_in[10];
  const float* W2    = (const float*)d_in[11];
  const float* b2    = (const float*)d_in[12];
  const float* ln1_g = (const float*)d_in[13];
  const float* ln1_b = (const float*)d_in[14];
  const float* ln2_g = (const float*)d_in[15];
  const float* ln2_b = (const float*)d_in[16];

  const size_t MB = 1ull << 20;
  char* ws = (char*)d_ws;
  ushort* Wqkv_b = (ushort*)(ws + 0 * MB);    // 6 MB  [3072,1024] (Q|K|V)
  ushort* Wo_b   = (ushort*)(ws + 6 * MB);    // 2 MB
  ushort* W1_b   = (ushort*)(ws + 8 * MB);    // 8 MB
  ushort* W2_b   = (ushort*)(ws + 16 * MB);   // 8 MB
  ushort* xn1    = (ushort*)(ws + 24 * MB);   // 16 MB
  ushort* Qb     = (ushort*)(ws + 40 * MB);   // 16 MB
  ushort* Kb     = (ushort*)(ws + 56 * MB);   // 16 MB
  ushort* Vt     = (ushort*)(ws + 72 * MB);   // 16 MB
  ushort* ctxb   = (ushort*)(ws + 88 * MB);   // 16 MB
  float*  x2     = (float*)(ws + 104 * MB);   // 32 MB
  ushort* xn2    = (ushort*)(ws + 136 * MB);  // 16 MB
  ushort* y1     = (ushort*)(ws + 152 * MB);  // 64 MB -> end 216 MB
  // bqkv aliases start of y1 (lifetime-disjoint: consumed before GELU GEMM writes y1)
  float*  bqkv   = (float*)(ws + 152 * MB);

  conv_all<<<12291, 256, 0, stream>>>(Wq, Wk, Wv, Wo, W1, W2, bq, bk, bv,
                                      Wqkv_b, Wo_b, W1_b, W2_b, bqkv);

  ln_kernel<<<8192, 256, 0, stream>>>(x, ln1_g, ln1_b, xn1);

  const float cs = 0.125f * 1.4426950408889634f;  // log2(e)/sqrt(64), folded into Q
  // Q|K projections (N=2048): 256^2 4-phase pipeline (hoisted frags)
  gemm256_kernel<EPI_QK><<<dim3(32, 8), 512, 0, stream>>>(
      xn1, Wqkv_b, bqkv, Qb, Kb, 1024, 2048, cs);
  // V^T projection: A = Wv (rows = v-dim), B = xn (rows = tokens) -> C[vdim, token]
  gemmW_kernel<EPI_VT><<<dim3(4, 64), 512, 0, stream>>>(
      Wqkv_b + (size_t)2048 * 1024, xn1, bqkv + 2048, nullptr, Vt, 1024, 8192);

  attn_kernel<<<1024, 256, 0, stream>>>(Qb, Kb, Vt, ctxb);

  gemmW_kernel<EPI_WO><<<dim3(32, 8), 512, 0, stream>>>(
      ctxb, Wo_b, bo, x, x2, 1024, 1024);

  ln_kernel<<<8192, 256, 0, stream>>>(x2, ln2_g, ln2_b, xn2);

  gemm256_kernel<EPI_GELU><<<dim3(32, 16), 512, 0, stream>>>(
      xn2, W1_b, b1, y1, nullptr, 1024, 4096, 1.0f);
  gemmW_kernel<EPI_OUT><<<dim3(32, 8), 512, 0, stream>>>(
      y1, W2_b, b2, x2, d_out, 4096, 1024);
}

// Round 10
// 499.901 us; speedup vs baseline: 1.0374x; 1.0374x over previous
//
#include <hip/hip_runtime.h>
#include <hip/hip_bf16.h>
#include <math.h>

typedef __attribute__((ext_vector_type(8))) short short8;
typedef __attribute__((ext_vector_type(4))) float f32x4;

#define MFMA_BF16 __builtin_amdgcn_mfma_f32_16x16x32_bf16

__device__ __forceinline__ ushort f2bf(float f) {
  union { __hip_bfloat16 h; ushort u; } c;
  c.h = __float2bfloat16(f);
  return c.u;
}
__device__ __forceinline__ void async_cp16(const ushort* g, ushort* l) {
  __builtin_amdgcn_global_load_lds(
      (const __attribute__((address_space(1))) void*)g,
      (__attribute__((address_space(3))) void*)l, 16, 0, 0);
}

// ------------- fused weight fp32->bf16 conversion + bias concat (one launch) -------------
__global__ __launch_bounds__(256) void conv_all(
    const float* __restrict__ Wq, const float* __restrict__ Wk,
    const float* __restrict__ Wv, const float* __restrict__ Wo,
    const float* __restrict__ W1, const float* __restrict__ W2,
    const float* __restrict__ bq, const float* __restrict__ bk,
    const float* __restrict__ bv,
    ushort* __restrict__ wqkv, ushort* __restrict__ wo,
    ushort* __restrict__ w1, ushort* __restrict__ w2,
    float* __restrict__ bqkv) {
  int i = blockIdx.x * 256 + threadIdx.x;   // float4 index
  if (i < 3145728) {
    const float* src; ushort* dst; int off;
    if (i < 786432)        { // Wq|Wk|Wv -> concatenated wqkv [3072,1024]
      dst = wqkv; off = i;
      if (i < 262144)      src = Wq + (size_t)i * 4;
      else if (i < 524288) src = Wk + (size_t)(i - 262144) * 4;
      else                 src = Wv + (size_t)(i - 524288) * 4;
    } else if (i < 1048576) { dst = wo; off = i - 786432;  src = Wo + (size_t)off * 4; }
    else if (i < 2097152)   { dst = w1; off = i - 1048576; src = W1 + (size_t)off * 4; }
    else                    { dst = w2; off = i - 2097152; src = W2 + (size_t)off * 4; }
    float4 v = *(const float4*)src;
    ushort4 o;
    o.x = f2bf(v.x); o.y = f2bf(v.y); o.z = f2bf(v.z); o.w = f2bf(v.w);
    ((ushort4*)dst)[off] = o;
  } else if (i < 3146496) {  // biases: 3 x 256 float4
    int off = i - 3145728;
    const float* src;
    if (off < 256)      src = bq + (size_t)off * 4;
    else if (off < 512) src = bk + (size_t)(off - 256) * 4;
    else                src = bv + (size_t)(off - 512) * 4;
    ((float4*)bqkv)[off] = *(const float4*)src;
  }
}

// ---------------- layernorm: one block per 1024-float row -> bf16 ----------------
__global__ __launch_bounds__(256) void ln_kernel(const float* __restrict__ x,
    const float* __restrict__ g, const float* __restrict__ b,
    ushort* __restrict__ out) {
  const int row = blockIdx.x, t = threadIdx.x;
  float4 v = ((const float4*)(x + (size_t)row * 1024))[t];
  float s  = v.x + v.y + v.z + v.w;
  float ss = v.x*v.x + v.y*v.y + v.z*v.z + v.w*v.w;
  #pragma unroll
  for (int off = 32; off >= 1; off >>= 1) {
    s  += __shfl_xor(s, off);
    ss += __shfl_xor(ss, off);
  }
  __shared__ float red[8];
  int wv = t >> 6, ln = t & 63;
  if (ln == 0) { red[wv] = s; red[4 + wv] = ss; }
  __syncthreads();
  float S  = red[0] + red[1] + red[2] + red[3];
  float SS = red[4] + red[5] + red[6] + red[7];
  float mu  = S * (1.0f/1024.0f);
  float var = SS * (1.0f/1024.0f) - mu*mu;
  float rs  = rsqrtf(var + 1e-6f);
  float4 gv = ((const float4*)g)[t];
  float4 bv = ((const float4*)b)[t];
  ushort4 o;
  o.x = f2bf((v.x-mu)*rs*gv.x + bv.x);
  o.y = f2bf((v.y-mu)*rs*gv.y + bv.y);
  o.z = f2bf((v.z-mu)*rs*gv.z + bv.z);
  o.w = f2bf((v.w-mu)*rs*gv.w + bv.w);
  ((ushort4*)(out + (size_t)row*1024))[t] = o;
}

enum { EPI_QK = 0, EPI_VT = 1, EPI_WO = 2, EPI_GELU = 3, EPI_OUT = 4 };

// ------- 256x256 bf16 GEMM, BK=64, 8 waves, 4-phase pipeline, hoisted frags (R9) -------
template <int EPI>
__global__ __launch_bounds__(512, 2) void gemm256_kernel(const ushort* __restrict__ A,
    const ushort* __restrict__ Bw, const float* __restrict__ bias,
    void* __restrict__ outp, void* __restrict__ outp2, int K, int N, float scale) {
  __shared__ ushort As[2][256 * 64];   // 32 KB per buf
  __shared__ ushort Bs[2][256 * 64];
  const int t = threadIdx.x;
  const int lane = t & 63, wave = t >> 6;
  const int col = lane & 15, quad = lane >> 4;
  const int m0 = blockIdx.x * 256, n0 = blockIdx.y * 256;
  const int wm = wave >> 2, wn = wave & 3;   // 2 x 4

  f32x4 acc[8][4];
  #pragma unroll
  for (int i = 0; i < 8; i++)
    #pragma unroll
    for (int j = 0; j < 4; j++)
      acc[i][j] = (f32x4){0.f, 0.f, 0.f, 0.f};

  size_t aoff[2], boff[2];
  int d0[2];
  #pragma unroll
  for (int i = 0; i < 2; i++) {
    int c = i * 512 + t, r = c >> 3, p = c & 7;
    aoff[i] = (size_t)(m0 + r) * K + (p ^ (r & 7)) * 8;
    boff[i] = (size_t)(n0 + r) * K + (p ^ (r & 7)) * 8;
    d0[i] = c * 8;
  }
  const size_t up = (size_t)128 * K;

  const int NT = K >> 6;
  // prologue: tile 0, order A0,B0,A1,B1; wait A0,B0 (A1,B1 in flight)
  #pragma unroll
  for (int i = 0; i < 2; i++) async_cp16(A  + aoff[i],      &As[0][d0[i]]);
  #pragma unroll
  for (int i = 0; i < 2; i++) async_cp16(Bw + boff[i],      &Bs[0][d0[i]]);
  #pragma unroll
  for (int i = 0; i < 2; i++) async_cp16(A  + aoff[i] + up, &As[0][8192 + d0[i]]);
  #pragma unroll
  for (int i = 0; i < 2; i++) async_cp16(Bw + boff[i] + up, &Bs[0][8192 + d0[i]]);
  asm volatile("s_waitcnt vmcnt(4)" ::: "memory");
  __builtin_amdgcn_sched_barrier(0);
  __builtin_amdgcn_s_barrier();
  __builtin_amdgcn_sched_barrier(0);

  short8 af0[4][2], af1[4][2], bf[2][2];
  for (int kt = 0; kt < NT; kt++) {
    const int cur = kt & 1, nxt = cur ^ 1;
    const size_t ko = (size_t)(kt + 1) << 6;
    const bool more = (kt + 1 < NT);

    // ---- ph0 (ha=0, hb=0): read af0 + bf(B0); stage A0(t+1)
    #pragma unroll
    for (int tml = 0; tml < 4; tml++) {
      const int row = wm * 64 + tml * 16 + col;
      #pragma unroll
      for (int c = 0; c < 2; c++)
        af0[tml][c] = *(const short8*)&As[cur][row * 64 + (((c * 4 + quad) ^ (row & 7)) * 8)];
    }
    #pragma unroll
    for (int tnl = 0; tnl < 2; tnl++) {
      const int row = wn * 32 + tnl * 16 + col;
      #pragma unroll
      for (int c = 0; c < 2; c++)
        bf[tnl][c] = *(const short8*)&Bs[cur][row * 64 + (((c * 4 + quad) ^ (row & 7)) * 8)];
    }
    if (more) {
      #pragma unroll
      for (int i = 0; i < 2; i++) async_cp16(A + aoff[i] + ko, &As[nxt][d0[i]]);
      asm volatile("s_waitcnt vmcnt(4)" ::: "memory");
    } else {
      asm volatile("s_waitcnt vmcnt(2)" ::: "memory");
    }
    __builtin_amdgcn_sched_barrier(0);
    __builtin_amdgcn_s_barrier();
    asm volatile("s_waitcnt lgkmcnt(0)" ::: "memory");
    __builtin_amdgcn_sched_barrier(0);
    __builtin_amdgcn_s_setprio(1);
    #pragma unroll
    for (int tml = 0; tml < 4; tml++)
      #pragma unroll
      for (int tnl = 0; tnl < 2; tnl++) {
        acc[tml][tnl] = MFMA_BF16(af0[tml][0], bf[tnl][0], acc[tml][tnl], 0, 0, 0);
        acc[tml][tnl] = MFMA_BF16(af0[tml][1], bf[tnl][1], acc[tml][tnl], 0, 0, 0);
      }
    __builtin_amdgcn_s_setprio(0);
    __builtin_amdgcn_sched_barrier(0);
    __builtin_amdgcn_s_barrier();
    __builtin_amdgcn_sched_barrier(0);

    // ---- ph1 (ha=1, hb=0): read af1; stage B0(t+1)
    #pragma unroll
    for (int tml = 0; tml < 4; tml++) {
      const int row = 128 + wm * 64 + tml * 16 + col;
      #pragma unroll
      for (int c = 0; c < 2; c++)
        af1[tml][c] = *(const short8*)&As[cur][row * 64 + (((c * 4 + quad) ^ (row & 7)) * 8)];
    }
    if (more) {
      #pragma unroll
      for (int i = 0; i < 2; i++) async_cp16(Bw + boff[i] + ko, &Bs[nxt][d0[i]]);
      asm volatile("s_waitcnt vmcnt(4)" ::: "memory");
    } else {
      asm volatile("s_waitcnt vmcnt(0)" ::: "memory");
    }
    __builtin_amdgcn_sched_barrier(0);
    __builtin_amdgcn_s_barrier();
    asm volatile("s_waitcnt lgkmcnt(0)" ::: "memory");
    __builtin_amdgcn_sched_barrier(0);
    __builtin_amdgcn_s_setprio(1);
    #pragma unroll
    for (int tml = 0; tml < 4; tml++)
      #pragma unroll
      for (int tnl = 0; tnl < 2; tnl++) {
        acc[4+tml][tnl] = MFMA_BF16(af1[tml][0], bf[tnl][0], acc[4+tml][tnl], 0, 0, 0);
        acc[4+tml][tnl] = MFMA_BF16(af1[tml][1], bf[tnl][1], acc[4+tml][tnl], 0, 0, 0);
      }
    __builtin_amdgcn_s_setprio(0);
    __builtin_amdgcn_sched_barrier(0);
    __builtin_amdgcn_s_barrier();
    __builtin_amdgcn_sched_barrier(0);

    // ---- ph2 (ha=0, hb=1): read bf(B1) (overwrite); stage A1(t+1)
    #pragma unroll
    for (int tnl = 0; tnl < 2; tnl++) {
      const int row = 128 + wn * 32 + tnl * 16 + col;
      #pragma unroll
      for (int c = 0; c < 2; c++)
        bf[tnl][c] = *(const short8*)&Bs[cur][row * 64 + (((c * 4 + quad) ^ (row & 7)) * 8)];
    }
    if (more) {
      #pragma unroll
      for (int i = 0; i < 2; i++) async_cp16(A + aoff[i] + up + ko, &As[nxt][8192 + d0[i]]);
      asm volatile("s_waitcnt vmcnt(4)" ::: "memory");
    } else {
      asm volatile("s_waitcnt vmcnt(0)" ::: "memory");
    }
    __builtin_amdgcn_sched_barrier(0);
    __builtin_amdgcn_s_barrier();
    asm volatile("s_waitcnt lgkmcnt(0)" ::: "memory");
    __builtin_amdgcn_sched_barrier(0);
    __builtin_amdgcn_s_setprio(1);
    #pragma unroll
    for (int tml = 0; tml < 4; tml++)
      #pragma unroll
      for (int tnl = 0; tnl < 2; tnl++) {
        acc[tml][2+tnl] = MFMA_BF16(af0[tml][0], bf[tnl][0], acc[tml][2+tnl], 0, 0, 0);
        acc[tml][2+tnl] = MFMA_BF16(af0[tml][1], bf[tnl][1], acc[tml][2+tnl], 0, 0, 0);
      }
    __builtin_amdgcn_s_setprio(0);
    __builtin_amdgcn_sched_barrier(0);
    __builtin_amdgcn_s_barrier();
    __builtin_amdgcn_sched_barrier(0);

    // ---- ph3 (ha=1, hb=1): no reads; stage B1(t+1)
    if (more) {
      #pragma unroll
      for (int i = 0; i < 2; i++) async_cp16(Bw + boff[i] + up + ko, &Bs[nxt][8192 + d0[i]]);
      asm volatile("s_waitcnt vmcnt(4)" ::: "memory");
    } else {
      asm volatile("s_waitcnt vmcnt(0)" ::: "memory");
    }
    __builtin_amdgcn_sched_barrier(0);
    __builtin_amdgcn_s_barrier();
    asm volatile("s_waitcnt lgkmcnt(0)" ::: "memory");
    __builtin_amdgcn_sched_barrier(0);
    __builtin_amdgcn_s_setprio(1);
    #pragma unroll
    for (int tml = 0; tml < 4; tml++)
      #pragma unroll
      for (int tnl = 0; tnl < 2; tnl++) {
        acc[4+tml][2+tnl] = MFMA_BF16(af1[tml][0], bf[tnl][0], acc[4+tml][2+tnl], 0, 0, 0);
        acc[4+tml][2+tnl] = MFMA_BF16(af1[tml][1], bf[tnl][1], acc[4+tml][2+tnl], 0, 0, 0);
      }
    __builtin_amdgcn_s_setprio(0);
    __builtin_amdgcn_sched_barrier(0);
    __builtin_amdgcn_s_barrier();
    __builtin_amdgcn_sched_barrier(0);
  }

  #pragma unroll
  for (int tm = 0; tm < 8; tm++) {
    const int ha = tm >> 2, tml = tm & 3;
    #pragma unroll
    for (int tn = 0; tn < 4; tn++) {
      const int hb = tn >> 1, tnl = tn & 1;
      const int n = n0 + hb * 128 + wn * 32 + tnl * 16 + col;
      const float bn = bias[n];
      #pragma unroll
      for (int r = 0; r < 4; r++) {
        const int m = m0 + ha * 128 + wm * 64 + tml * 16 + quad * 4 + r;
        float v = acc[tm][tn][r] + bn;
        if (EPI == EPI_QK) {
          int nl = n & 1023, h = nl >> 6, hd = nl & 63;
          int bb = m >> 11, s2 = m & 2047;
          if (n < 1024)
            ((ushort*)outp)[(((size_t)(bb * 16 + h) * 2048 + s2) * 64) + hd] = f2bf(v * scale);
          else
            ((ushort*)outp2)[(((size_t)(bb * 16 + h) * 2048 + s2) * 64) + hd] = f2bf(v);
        } else {  // EPI_GELU
          float u = v * 0.7978845608028654f * (1.0f + 0.044715f * v * v);
          float e = __builtin_amdgcn_exp2f(u * 2.885390081777927f);  // e^{2u}
          float th = 1.0f - 2.0f * __builtin_amdgcn_rcpf(e + 1.0f);
          ((ushort*)outp)[(size_t)m * N + n] = f2bf(0.5f * v * (1.0f + th));
        }
      }
    }
  }
}

// ------- 128x256 bf16 GEMM, BK=64, 8 waves, 2-phase counted pipeline (VT/WO/OUT) -------
// 16 MFMA per phase (gemm256-class mass). Units/K-tile: A (128x64, 2 loads/thr),
// B0 (n 0-127, 2), B1 (n 128-255, 2). ph0: read af+bf(B0), stage A,B0(t+1), vmcnt(4);
// ph1: read bf(B1), stage B1(t+1), vmcnt(2). Per-thread ledger: entering ph0(t)
// outstanding = B1(t)[2]; after ph0 stage = 6 -> vmcnt(4) proves B1(t) landed (ph1
// reads it); after ph1 stage = 6 -> vmcnt(2) proves A,B0(t+1) landed (next ph0 reads).
// Never drains in steady state; tails 0/0; prologue vmcnt(2). WAR: staged buf's last
// readers completed >=2 barriers earlier. Same row&7 chunk-XOR swizzle (0-conflict).
// Grid: 1D 256 blocks (exactly 1/CU) with XCD-chunked decode (8 XCDs x 32 contiguous).
template <int EPI>
__global__ __launch_bounds__(512, 2) void gemmH_kernel(const ushort* __restrict__ A,
    const ushort* __restrict__ Bw, const float* __restrict__ bias,
    const float* __restrict__ res, void* __restrict__ outp, int K, int N, int gx) {
  __shared__ ushort As[2][128 * 64];   // 16 KB per buf
  __shared__ ushort Bs[2][256 * 64];   // 32 KB per buf
  const int t = threadIdx.x;
  const int lane = t & 63, wave = t >> 6;
  const int col = lane & 15, quad = lane >> 4;
  const int bl = (blockIdx.x & 7) * 32 + (blockIdx.x >> 3);   // XCD-chunked (grid=256)
  const int m0 = (bl % gx) * 128, n0 = (bl / gx) * 256;
  const int wm = wave >> 2, wn = wave & 3;   // 2 x 4; per-wave out 64 x 64

  f32x4 acc[4][4];   // [tml][hb*2+tnl]
  #pragma unroll
  for (int i = 0; i < 4; i++)
    #pragma unroll
    for (int j = 0; j < 4; j++)
      acc[i][j] = (f32x4){0.f, 0.f, 0.f, 0.f};

  size_t aoff[2], boff[2];
  int ad0[2], bd0[2];
  #pragma unroll
  for (int i = 0; i < 2; i++) {
    int c = i * 512 + t, r = c >> 3, p = c & 7;   // r in 0..127
    aoff[i] = (size_t)(m0 + r) * K + (p ^ (r & 7)) * 8;
    boff[i] = (size_t)(n0 + r) * K + (p ^ (r & 7)) * 8;
    ad0[i] = c * 8; bd0[i] = c * 8;
  }
  const size_t upB = (size_t)128 * K;   // B1 rows n0+128..255

  const int NT = K >> 6;
  // prologue: A, B0, B1 of tile 0; wait A,B0 (B1 in flight, covered by kt0's vmcnt(4))
  #pragma unroll
  for (int i = 0; i < 2; i++) async_cp16(A  + aoff[i],       &As[0][ad0[i]]);
  #pragma unroll
  for (int i = 0; i < 2; i++) async_cp16(Bw + boff[i],       &Bs[0][bd0[i]]);
  #pragma unroll
  for (int i = 0; i < 2; i++) async_cp16(Bw + boff[i] + upB, &Bs[0][8192 + bd0[i]]);
  asm volatile("s_waitcnt vmcnt(2)" ::: "memory");
  __builtin_amdgcn_sched_barrier(0);
  __builtin_amdgcn_s_barrier();
  __builtin_amdgcn_sched_barrier(0);

  short8 af[4][2], bf[2][2];
  for (int kt = 0; kt < NT; kt++) {
    const int cur = kt & 1, nxt = cur ^ 1;
    const size_t ko = (size_t)(kt + 1) << 6;
    const bool more = (kt + 1 < NT);

    // ---- ph0 (hb=0): read af (8) + bf(B0) (4); stage A(t+1), B0(t+1); vmcnt(4)
    #pragma unroll
    for (int tml = 0; tml < 4; tml++) {
      const int row = wm * 64 + tml * 16 + col;
      #pragma unroll
      for (int c = 0; c < 2; c++)
        af[tml][c] = *(const short8*)&As[cur][row * 64 + (((c * 4 + quad) ^ (row & 7)) * 8)];
    }
    #pragma unroll
    for (int tnl = 0; tnl < 2; tnl++) {
      const int row = wn * 32 + tnl * 16 + col;
      #pragma unroll
      for (int c = 0; c < 2; c++)
        bf[tnl][c] = *(const short8*)&Bs[cur][row * 64 + (((c * 4 + quad) ^ (row & 7)) * 8)];
    }
    if (more) {
      #pragma unroll
      for (int i = 0; i < 2; i++) async_cp16(A  + aoff[i] + ko, &As[nxt][ad0[i]]);
      #pragma unroll
      for (int i = 0; i < 2; i++) async_cp16(Bw + boff[i] + ko, &Bs[nxt][bd0[i]]);
      asm volatile("s_waitcnt vmcnt(4)" ::: "memory");
    } else {
      asm volatile("s_waitcnt vmcnt(0)" ::: "memory");
    }
    __builtin_amdgcn_sched_barrier(0);
    __builtin_amdgcn_s_barrier();
    asm volatile("s_waitcnt lgkmcnt(0)" ::: "memory");
    __builtin_amdgcn_sched_barrier(0);
    __builtin_amdgcn_s_setprio(1);
    #pragma unroll
    for (int tml = 0; tml < 4; tml++)
      #pragma unroll
      for (int tnl = 0; tnl < 2; tnl++) {
        acc[tml][tnl] = MFMA_BF16(af[tml][0], bf[tnl][0], acc[tml][tnl], 0, 0, 0);
        acc[tml][tnl] = MFMA_BF16(af[tml][1], bf[tnl][1], acc[tml][tnl], 0, 0, 0);
      }
    __builtin_amdgcn_s_setprio(0);
    __builtin_amdgcn_sched_barrier(0);
    __builtin_amdgcn_s_barrier();
    __builtin_amdgcn_sched_barrier(0);

    // ---- ph1 (hb=1): read bf(B1); stage B1(t+1); vmcnt(2)
    #pragma unroll
    for (int tnl = 0; tnl < 2; tnl++) {
      const int rp = wn * 32 + tnl * 16 + col;   // row-in-unit; (128+rp)&7 == rp&7
      #pragma unroll
      for (int c = 0; c < 2; c++)
        bf[tnl][c] = *(const short8*)&Bs[cur][8192 + rp * 64 + (((c * 4 + quad) ^ (rp & 7)) * 8)];
    }
    if (more) {
      #pragma unroll
      for (int i = 0; i < 2; i++) async_cp16(Bw + boff[i] + upB + ko, &Bs[nxt][8192 + bd0[i]]);
      asm volatile("s_waitcnt vmcnt(2)" ::: "memory");
    } else {
      asm volatile("s_waitcnt vmcnt(0)" ::: "memory");
    }
    __builtin_amdgcn_sched_barrier(0);
    __builtin_amdgcn_s_barrier();
    asm volatile("s_waitcnt lgkmcnt(0)" ::: "memory");
    __builtin_amdgcn_sched_barrier(0);
    __builtin_amdgcn_s_setprio(1);
    #pragma unroll
    for (int tml = 0; tml < 4; tml++)
      #pragma unroll
      for (int tnl = 0; tnl < 2; tnl++) {
        acc[tml][2+tnl] = MFMA_BF16(af[tml][0], bf[tnl][0], acc[tml][2+tnl], 0, 0, 0);
        acc[tml][2+tnl] = MFMA_BF16(af[tml][1], bf[tnl][1], acc[tml][2+tnl], 0, 0, 0);
      }
    __builtin_amdgcn_s_setprio(0);
    __builtin_amdgcn_sched_barrier(0);
    __builtin_amdgcn_s_barrier();
    __builtin_amdgcn_sched_barrier(0);
  }

  #pragma unroll
  for (int tml = 0; tml < 4; tml++) {
    #pragma unroll
    for (int tn = 0; tn < 4; tn++) {
      const int hb = tn >> 1, tnl = tn & 1;
      const int n = n0 + hb * 128 + wn * 32 + tnl * 16 + col;
      #pragma unroll
      for (int r = 0; r < 4; r++) {
        const int m = m0 + wm * 64 + tml * 16 + quad * 4 + r;
        float v = acc[tml][tn][r];
        if (EPI == EPI_VT) {
          // A=Wv (m = v-dim), Bw=xn (n = token); bias indexed by m
          float vv = v + bias[m];
          int h = m >> 6, hd = m & 63, bb = n >> 11, s2 = n & 2047;
          ((ushort*)outp)[((size_t)((bb * 16 + h) * 64 + hd)) * 2048 + s2] = f2bf(vv);
        } else {  // EPI_WO / EPI_OUT: float out + bias + residual
          ((float*)outp)[(size_t)m * N + n] = v + bias[n] + res[(size_t)m * N + n];
        }
      }
    }
  }
}

// ---------------- flash attention v13 (R9 proven, 108.3 us) ----------
__global__ __launch_bounds__(256) void attn_kernel(const ushort* __restrict__ Qb,
    const ushort* __restrict__ Kb, const ushort* __restrict__ Vt,
    ushort* __restrict__ ctx) {
  const int lane = threadIdx.x & 63, wave = threadIdx.x >> 6;
  const int col = lane & 15, quad = lane >> 4;
  const int bx = blockIdx.x;
  const int bh = bx & 63;          // XCD = bh % 8 for every q-tile of this head
  const int qt = bx >> 6;          // 0..15
  const int qbase = qt * 128 + wave * 32;
  const ushort* Qh = Qb + (size_t)bh * 2048 * 64;
  const ushort* Kh = Kb + (size_t)bh * 2048 * 64;
  const ushort* Vh = Vt + (size_t)bh * 64 * 2048;

  short8 qa[2][2];
  #pragma unroll
  for (int qg = 0; qg < 2; qg++) {
    const ushort* Qr = Qh + (size_t)(qbase + qg * 16 + col) * 64 + quad * 8;
    qa[qg][0] = *(const short8*)Qr;
    qa[qg][1] = *(const short8*)(Qr + 32);
  }

  short8 ones8;
  #pragma unroll
  for (int i = 0; i < 8; i++) ones8[i] = (short)0x3F80;   // 1.0 bf16

  f32x4 Ot[2][4], Ol[2];
  #pragma unroll
  for (int qg = 0; qg < 2; qg++) {
    Ol[qg] = (f32x4){0.f, 0.f, 0.f, 0.f};
    #pragma unroll
    for (int dt = 0; dt < 4; dt++) Ot[qg][dt] = (f32x4){0.f, 0.f, 0.f, 0.f};
  }

  __shared__ ushort Ks[2][2][64 * 32];   // [buf][d-half][key*32 + swz-chunk] 16 KB
  __shared__ ushort Vs[2][2][64 * 32];   // [buf][key-half][d*32 + swz-chunk] 16 KB
  __shared__ ushort P_lds[4][16][64];    // [wave][q][8 x 16B chunks, swz] 8 KB

  const int lrow = lane >> 2;
  const int srow = wave * 16 + lrow;                       // row this lane stages
  const int lcol = ((lane & 3) ^ ((srow >> 1) & 3)) * 8;   // swizzled 16B chunk in 64B half
  const ushort* Kg = Kh + (size_t)srow * 64 + lcol;        // + kb*64 (+32 for half 1)
  const ushort* Vg = Vh + (size_t)srow * 2048 + lcol;      // + kb   (+32 for half 1)
  const int so = (wave * 16) * 32;

  const int kvswz = (col >> 1) & 3;   // fragment-read XOR (rows kt*16+col: (row>>1)&3)
  const int pswz = col & 7;           // P chunk XOR

  // prologue: stage chunk 0 into buf 0
  async_cp16(Kg,      &Ks[0][0][so]);
  async_cp16(Kg + 32, &Ks[0][1][so]);
  async_cp16(Vg,      &Vs[0][0][so]);
  async_cp16(Vg + 32, &Vs[0][1][so]);
  __syncthreads();

  int cur = 0;
  for (int kb = 0; kb < 2048; kb += 64) {
    if (kb + 64 < 2048) {
      const int nxt = cur ^ 1;
      async_cp16(Kg + (size_t)(kb + 64) * 64,      &Ks[nxt][0][so]);
      async_cp16(Kg + (size_t)(kb + 64) * 64 + 32, &Ks[nxt][1][so]);
      async_cp16(Vg + (kb + 64),                   &Vs[nxt][0][so]);
      async_cp16(Vg + (kb + 64) + 32,              &Vs[nxt][1][so]);
    }

    // fragments from LDS (shared across the 2 q-groups), swizzled reads
    short8 kf[4][2], vf[4][2];
    #pragma unroll
    for (int kt = 0; kt < 4; kt++)
      #pragma unroll
      for (int c = 0; c < 2; c++)
        kf[kt][c] = *(const short8*)&Ks[cur][c][(kt * 16 + col) * 32 + (quad ^ kvswz) * 8];
    #pragma unroll
    for (int dt = 0; dt < 4; dt++)
      #pragma unroll
      for (int c = 0; c < 2; c++)
        vf[dt][c] = *(const short8*)&Vs[cur][c][(dt * 16 + col) * 32 + (quad ^ kvswz) * 8];

    #pragma unroll
    for (int qg = 0; qg < 2; qg++) {
      f32x4 s[4];
      __builtin_amdgcn_s_setprio(1);
      #pragma unroll
      for (int kt = 0; kt < 4; kt++) {
        s[kt] = (f32x4){0.f, 0.f, 0.f, 0.f};
        s[kt] = MFMA_BF16(kf[kt][0], qa[qg][0], s[kt], 0, 0, 0);
        s[kt] = MFMA_BF16(kf[kt][1], qa[qg][1], s[kt], 0, 0, 0);
      }
      __builtin_amdgcn_s_setprio(0);
      ushort(*P)[64] = P_lds[wave];
      #pragma unroll
      for (int kt = 0; kt < 4; kt++) {
        float p0 = __builtin_amdgcn_exp2f(s[kt][0]);
        float p1 = __builtin_amdgcn_exp2f(s[kt][1]);
        float p2 = __builtin_amdgcn_exp2f(s[kt][2]);
        float p3 = __builtin_amdgcn_exp2f(s[kt][3]);
        uint2 pk;
        asm("v_cvt_pk_bf16_f32 %0, %1, %2" : "=v"(pk.x) : "v"(p0), "v"(p1));
        asm("v_cvt_pk_bf16_f32 %0, %1, %2" : "=v"(pk.y) : "v"(p2), "v"(p3));
        *(uint2*)&P[col][(((2 * kt + (quad >> 1)) ^ pswz) * 8) + (quad & 1) * 4] = pk;
      }
      // PV for this qg (same-wave LDS RAW handled in-order; no barrier needed)
      #pragma unroll
      for (int c = 0; c < 2; c++) {
        short8 pf = *(const short8*)&P_lds[wave][col][((4 * c + quad) ^ pswz) * 8];
        __builtin_amdgcn_s_setprio(1);
        #pragma unroll
        for (int dt = 0; dt < 4; dt++)
          Ot[qg][dt] = MFMA_BF16(vf[dt][c], pf, Ot[qg][dt], 0, 0, 0);
        Ol[qg] = MFMA_BF16(ones8, pf, Ol[qg], 0, 0, 0);   // l-sum on MFMA pipe
        __builtin_amdgcn_s_setprio(0);
      }
    }
    __syncthreads();
    cur ^= 1;
  }

  const int bb = bh >> 4, h = bh & 15;
  #pragma unroll
  for (int qg = 0; qg < 2; qg++) {
    float inv = __builtin_amdgcn_rcpf(Ol[qg][0]);   // identical in all lanes/regs
    const int q = qbase + qg * 16 + col;
    size_t base = ((size_t)(bb * 2048 + q)) * 1024 + h * 64;
    #pragma unroll
    for (int dt = 0; dt < 4; dt++) {
      ushort4 o;
      o.x = f2bf(Ot[qg][dt][0] * inv);
      o.y = f2bf(Ot[qg][dt][1] * inv);
      o.z = f2bf(Ot[qg][dt][2] * inv);
      o.w = f2bf(Ot[qg][dt][3] * inv);
      *(ushort4*)&ctx[base + dt * 16 + quad * 4] = o;
    }
  }
}

// ---------------- host ----------------
extern "C" void kernel_launch(void* const* d_in, const int* in_sizes, int n_in,
                              void* d_out, int out_size, void* d_ws, size_t ws_size,
                              hipStream_t stream) {
  const float* x     = (const float*)d_in[0];
  const float* Wq    = (const float*)d_in[1];
  const float* bq    = (const float*)d_in[2];
  const float* Wk    = (const float*)d_in[3];
  const float* bk    = (const float*)d_in[4];
  const float* Wv    = (const float*)d_in[5];
  const float* bv    = (const float*)d_in[6];
  const float* Wo    = (const float*)d_in[7];
  const float* bo    = (const float*)d_in[8];
  const float* W1    = (const float*)d_in[9];
  const float* b1    = (const float*)d_in[10];
  const float* W2    = (const float*)d_in[11];
  const float* b2    = (const float*)d_in[12];
  const float* ln1_g = (const float*)d_in[13];
  const float* ln1_b = (const float*)d_in[14];
  const float* ln2_g = (const float*)d_in[15];
  const float* ln2_b = (const float*)d_in[16];

  const size_t MB = 1ull << 20;
  char* ws = (char*)d_ws;
  ushort* Wqkv_b = (ushort*)(ws + 0 * MB);    // 6 MB  [3072,1024] (Q|K|V)
  ushort* Wo_b   = (ushort*)(ws + 6 * MB);    // 2 MB
  ushort* W1_b   = (ushort*)(ws + 8 * MB);    // 8 MB
  ushort* W2_b   = (ushort*)(ws + 16 * MB);   // 8 MB
  ushort* xn1    = (ushort*)(ws + 24 * MB);   // 16 MB
  ushort* Qb     = (ushort*)(ws + 40 * MB);   // 16 MB
  ushort* Kb     = (ushort*)(ws + 56 * MB);   // 16 MB
  ushort* Vt     = (ushort*)(ws + 72 * MB);   // 16 MB
  ushort* ctxb   = (ushort*)(ws + 88 * MB);   // 16 MB
  float*  x2     = (float*)(ws + 104 * MB);   // 32 MB
  ushort* xn2    = (ushort*)(ws + 136 * MB);  // 16 MB
  ushort* y1     = (ushort*)(ws + 152 * MB);  // 64 MB -> end 216 MB
  // bqkv aliases start of y1 (lifetime-disjoint: consumed before GELU GEMM writes y1)
  float*  bqkv   = (float*)(ws + 152 * MB);

  conv_all<<<12291, 256, 0, stream>>>(Wq, Wk, Wv, Wo, W1, W2, bq, bk, bv,
                                      Wqkv_b, Wo_b, W1_b, W2_b, bqkv);

  ln_kernel<<<8192, 256, 0, stream>>>(x, ln1_g, ln1_b, xn1);

  const float cs = 0.125f * 1.4426950408889634f;  // log2(e)/sqrt(64), folded into Q
  // Q|K projections (N=2048): 256^2 4-phase pipeline (hoisted frags)
  gemm256_kernel<EPI_QK><<<dim3(32, 8), 512, 0, stream>>>(
      xn1, Wqkv_b, bqkv, Qb, Kb, 1024, 2048, cs);
  // V^T projection: A = Wv (rows = v-dim), B = xn (rows = tokens) -> C[vdim, token]
  gemmH_kernel<EPI_VT><<<256, 512, 0, stream>>>(
      Wqkv_b + (size_t)2048 * 1024, xn1, bqkv + 2048, nullptr, Vt, 1024, 8192, 8);

  attn_kernel<<<1024, 256, 0, stream>>>(Qb, Kb, Vt, ctxb);

  gemmH_kernel<EPI_WO><<<256, 512, 0, stream>>>(
      ctxb, Wo_b, bo, x, x2, 1024, 1024, 64);

  ln_kernel<<<8192, 256, 0, stream>>>(x2, ln2_g, ln2_b, xn2);

  gemm256_kernel<EPI_GELU><<<dim3(32, 16), 512, 0, stream>>>(
      xn2, W1_b, b1, y1, nullptr, 1024, 4096, 1.0f);
  gemmH_kernel<EPI_OUT><<<256, 512, 0, stream>>>(
      y1, W2_b, b2, x2, d_out, 4096, 1024, 64);
}

// Round 11
// 482.447 us; speedup vs baseline: 1.0749x; 1.0362x over previous
//
#include <hip/hip_runtime.h>
#include <hip/hip_bf16.h>
#include <math.h>

typedef __attribute__((ext_vector_type(8))) short short8;
typedef __attribute__((ext_vector_type(4))) float f32x4;

#define MFMA_BF16 __builtin_amdgcn_mfma_f32_16x16x32_bf16

__device__ __forceinline__ ushort f2bf(float f) {
  union { __hip_bfloat16 h; ushort u; } c;
  c.h = __float2bfloat16(f);
  return c.u;
}
__device__ __forceinline__ void async_cp16(const ushort* g, ushort* l) {
  __builtin_amdgcn_global_load_lds(
      (const __attribute__((address_space(1))) void*)g,
      (__attribute__((address_space(3))) void*)l, 16, 0, 0);
}

// ------------- fused weight fp32->bf16 conversion + bias concat (one launch) -------------
__global__ __launch_bounds__(256) void conv_all(
    const float* __restrict__ Wq, const float* __restrict__ Wk,
    const float* __restrict__ Wv, const float* __restrict__ Wo,
    const float* __restrict__ W1, const float* __restrict__ W2,
    const float* __restrict__ bq, const float* __restrict__ bk,
    const float* __restrict__ bv,
    ushort* __restrict__ wqkv, ushort* __restrict__ wo,
    ushort* __restrict__ w1, ushort* __restrict__ w2,
    float* __restrict__ bqkv) {
  int i = blockIdx.x * 256 + threadIdx.x;   // float4 index
  if (i < 3145728) {
    const float* src; ushort* dst; int off;
    if (i < 786432)        { // Wq|Wk|Wv -> concatenated wqkv [3072,1024]
      dst = wqkv; off = i;
      if (i < 262144)      src = Wq + (size_t)i * 4;
      else if (i < 524288) src = Wk + (size_t)(i - 262144) * 4;
      else                 src = Wv + (size_t)(i - 524288) * 4;
    } else if (i < 1048576) { dst = wo; off = i - 786432;  src = Wo + (size_t)off * 4; }
    else if (i < 2097152)   { dst = w1; off = i - 1048576; src = W1 + (size_t)off * 4; }
    else                    { dst = w2; off = i - 2097152; src = W2 + (size_t)off * 4; }
    float4 v = *(const float4*)src;
    ushort4 o;
    o.x = f2bf(v.x); o.y = f2bf(v.y); o.z = f2bf(v.z); o.w = f2bf(v.w);
    ((ushort4*)dst)[off] = o;
  } else if (i < 3146496) {  // biases: 3 x 256 float4
    int off = i - 3145728;
    const float* src;
    if (off < 256)      src = bq + (size_t)off * 4;
    else if (off < 512) src = bk + (size_t)(off - 256) * 4;
    else                src = bv + (size_t)(off - 512) * 4;
    ((float4*)bqkv)[off] = *(const float4*)src;
  }
}

// ---------------- layernorm: one block per 1024-float row -> bf16 ----------------
__global__ __launch_bounds__(256) void ln_kernel(const float* __restrict__ x,
    const float* __restrict__ g, const float* __restrict__ b,
    ushort* __restrict__ out) {
  const int row = blockIdx.x, t = threadIdx.x;
  float4 v = ((const float4*)(x + (size_t)row * 1024))[t];
  float s  = v.x + v.y + v.z + v.w;
  float ss = v.x*v.x + v.y*v.y + v.z*v.z + v.w*v.w;
  #pragma unroll
  for (int off = 32; off >= 1; off >>= 1) {
    s  += __shfl_xor(s, off);
    ss += __shfl_xor(ss, off);
  }
  __shared__ float red[8];
  int wv = t >> 6, ln = t & 63;
  if (ln == 0) { red[wv] = s; red[4 + wv] = ss; }
  __syncthreads();
  float S  = red[0] + red[1] + red[2] + red[3];
  float SS = red[4] + red[5] + red[6] + red[7];
  float mu  = S * (1.0f/1024.0f);
  float var = SS * (1.0f/1024.0f) - mu*mu;
  float rs  = rsqrtf(var + 1e-6f);
  float4 gv = ((const float4*)g)[t];
  float4 bv = ((const float4*)b)[t];
  ushort4 o;
  o.x = f2bf((v.x-mu)*rs*gv.x + bv.x);
  o.y = f2bf((v.y-mu)*rs*gv.y + bv.y);
  o.z = f2bf((v.z-mu)*rs*gv.z + bv.z);
  o.w = f2bf((v.w-mu)*rs*gv.w + bv.w);
  ((ushort4*)(out + (size_t)row*1024))[t] = o;
}

enum { EPI_QK = 0, EPI_VT = 1, EPI_WO = 2, EPI_GELU = 3, EPI_OUT = 4 };

// ------- 256x256 bf16 GEMM, BK=64, 8 waves, 4-phase pipeline, ONE barrier/phase -------
// R9 schedule with the bottom barrier per phase REMOVED (hazard ledger: RAW of each
// unit is proven at a later phase's top-barrier vmcnt; WAR separated by >=1 top
// barrier + reader's own lgkmcnt-before-MFMA). 4 barriers per K-tile (was 8).
template <int EPI>
__global__ __launch_bounds__(512, 2) void gemm256_kernel(const ushort* __restrict__ A,
    const ushort* __restrict__ Bw, const float* __restrict__ bias,
    void* __restrict__ outp, void* __restrict__ outp2, int K, int N, float scale) {
  __shared__ ushort As[2][256 * 64];   // 32 KB per buf
  __shared__ ushort Bs[2][256 * 64];
  const int t = threadIdx.x;
  const int lane = t & 63, wave = t >> 6;
  const int col = lane & 15, quad = lane >> 4;
  const int m0 = blockIdx.x * 256, n0 = blockIdx.y * 256;
  const int wm = wave >> 2, wn = wave & 3;   // 2 x 4

  f32x4 acc[8][4];
  #pragma unroll
  for (int i = 0; i < 8; i++)
    #pragma unroll
    for (int j = 0; j < 4; j++)
      acc[i][j] = (f32x4){0.f, 0.f, 0.f, 0.f};

  size_t aoff[2], boff[2];
  int d0[2];
  #pragma unroll
  for (int i = 0; i < 2; i++) {
    int c = i * 512 + t, r = c >> 3, p = c & 7;
    aoff[i] = (size_t)(m0 + r) * K + (p ^ (r & 7)) * 8;
    boff[i] = (size_t)(n0 + r) * K + (p ^ (r & 7)) * 8;
    d0[i] = c * 8;
  }
  const size_t up = (size_t)128 * K;

  const int NT = K >> 6;
  // prologue: tile 0, order A0,B0,A1,B1; wait A0,B0 (A1,B1 in flight)
  #pragma unroll
  for (int i = 0; i < 2; i++) async_cp16(A  + aoff[i],      &As[0][d0[i]]);
  #pragma unroll
  for (int i = 0; i < 2; i++) async_cp16(Bw + boff[i],      &Bs[0][d0[i]]);
  #pragma unroll
  for (int i = 0; i < 2; i++) async_cp16(A  + aoff[i] + up, &As[0][8192 + d0[i]]);
  #pragma unroll
  for (int i = 0; i < 2; i++) async_cp16(Bw + boff[i] + up, &Bs[0][8192 + d0[i]]);
  asm volatile("s_waitcnt vmcnt(4)" ::: "memory");
  __builtin_amdgcn_sched_barrier(0);
  __builtin_amdgcn_s_barrier();
  __builtin_amdgcn_sched_barrier(0);

  short8 af0[4][2], af1[4][2], bf[2][2];
  for (int kt = 0; kt < NT; kt++) {
    const int cur = kt & 1, nxt = cur ^ 1;
    const size_t ko = (size_t)(kt + 1) << 6;
    const bool more = (kt + 1 < NT);

    // ---- ph0: read af0 + bf(B0); stage A0(t+1); vmcnt(4); barrier; MFMA quad (0,0)
    #pragma unroll
    for (int tml = 0; tml < 4; tml++) {
      const int row = wm * 64 + tml * 16 + col;
      #pragma unroll
      for (int c = 0; c < 2; c++)
        af0[tml][c] = *(const short8*)&As[cur][row * 64 + (((c * 4 + quad) ^ (row & 7)) * 8)];
    }
    #pragma unroll
    for (int tnl = 0; tnl < 2; tnl++) {
      const int row = wn * 32 + tnl * 16 + col;
      #pragma unroll
      for (int c = 0; c < 2; c++)
        bf[tnl][c] = *(const short8*)&Bs[cur][row * 64 + (((c * 4 + quad) ^ (row & 7)) * 8)];
    }
    if (more) {
      #pragma unroll
      for (int i = 0; i < 2; i++) async_cp16(A + aoff[i] + ko, &As[nxt][d0[i]]);
      asm volatile("s_waitcnt vmcnt(4)" ::: "memory");
    } else {
      asm volatile("s_waitcnt vmcnt(2)" ::: "memory");
    }
    __builtin_amdgcn_sched_barrier(0);
    __builtin_amdgcn_s_barrier();
    asm volatile("s_waitcnt lgkmcnt(0)" ::: "memory");
    __builtin_amdgcn_sched_barrier(0);
    __builtin_amdgcn_s_setprio(1);
    #pragma unroll
    for (int tml = 0; tml < 4; tml++)
      #pragma unroll
      for (int tnl = 0; tnl < 2; tnl++) {
        acc[tml][tnl] = MFMA_BF16(af0[tml][0], bf[tnl][0], acc[tml][tnl], 0, 0, 0);
        acc[tml][tnl] = MFMA_BF16(af0[tml][1], bf[tnl][1], acc[tml][tnl], 0, 0, 0);
      }
    __builtin_amdgcn_s_setprio(0);

    // ---- ph1: read af1; stage B0(t+1); vmcnt(4); barrier; MFMA quad (1,0)
    #pragma unroll
    for (int tml = 0; tml < 4; tml++) {
      const int row = 128 + wm * 64 + tml * 16 + col;
      #pragma unroll
      for (int c = 0; c < 2; c++)
        af1[tml][c] = *(const short8*)&As[cur][row * 64 + (((c * 4 + quad) ^ (row & 7)) * 8)];
    }
    if (more) {
      #pragma unroll
      for (int i = 0; i < 2; i++) async_cp16(Bw + boff[i] + ko, &Bs[nxt][d0[i]]);
      asm volatile("s_waitcnt vmcnt(4)" ::: "memory");
    } else {
      asm volatile("s_waitcnt vmcnt(0)" ::: "memory");
    }
    __builtin_amdgcn_sched_barrier(0);
    __builtin_amdgcn_s_barrier();
    asm volatile("s_waitcnt lgkmcnt(0)" ::: "memory");
    __builtin_amdgcn_sched_barrier(0);
    __builtin_amdgcn_s_setprio(1);
    #pragma unroll
    for (int tml = 0; tml < 4; tml++)
      #pragma unroll
      for (int tnl = 0; tnl < 2; tnl++) {
        acc[4+tml][tnl] = MFMA_BF16(af1[tml][0], bf[tnl][0], acc[4+tml][tnl], 0, 0, 0);
        acc[4+tml][tnl] = MFMA_BF16(af1[tml][1], bf[tnl][1], acc[4+tml][tnl], 0, 0, 0);
      }
    __builtin_amdgcn_s_setprio(0);

    // ---- ph2: read bf(B1) (overwrite); stage A1(t+1); vmcnt(4); barrier; quad (0,1)
    #pragma unroll
    for (int tnl = 0; tnl < 2; tnl++) {
      const int row = 128 + wn * 32 + tnl * 16 + col;
      #pragma unroll
      for (int c = 0; c < 2; c++)
        bf[tnl][c] = *(const short8*)&Bs[cur][row * 64 + (((c * 4 + quad) ^ (row & 7)) * 8)];
    }
    if (more) {
      #pragma unroll
      for (int i = 0; i < 2; i++) async_cp16(A + aoff[i] + up + ko, &As[nxt][8192 + d0[i]]);
      asm volatile("s_waitcnt vmcnt(4)" ::: "memory");
    } else {
      asm volatile("s_waitcnt vmcnt(0)" ::: "memory");
    }
    __builtin_amdgcn_sched_barrier(0);
    __builtin_amdgcn_s_barrier();
    asm volatile("s_waitcnt lgkmcnt(0)" ::: "memory");
    __builtin_amdgcn_sched_barrier(0);
    __builtin_amdgcn_s_setprio(1);
    #pragma unroll
    for (int tml = 0; tml < 4; tml++)
      #pragma unroll
      for (int tnl = 0; tnl < 2; tnl++) {
        acc[tml][2+tnl] = MFMA_BF16(af0[tml][0], bf[tnl][0], acc[tml][2+tnl], 0, 0, 0);
        acc[tml][2+tnl] = MFMA_BF16(af0[tml][1], bf[tnl][1], acc[tml][2+tnl], 0, 0, 0);
      }
    __builtin_amdgcn_s_setprio(0);

    // ---- ph3: no reads; stage B1(t+1); vmcnt(4); barrier; MFMA quad (1,1)
    if (more) {
      #pragma unroll
      for (int i = 0; i < 2; i++) async_cp16(Bw + boff[i] + up + ko, &Bs[nxt][8192 + d0[i]]);
      asm volatile("s_waitcnt vmcnt(4)" ::: "memory");
    } else {
      asm volatile("s_waitcnt vmcnt(0)" ::: "memory");
    }
    __builtin_amdgcn_sched_barrier(0);
    __builtin_amdgcn_s_barrier();
    asm volatile("s_waitcnt lgkmcnt(0)" ::: "memory");
    __builtin_amdgcn_sched_barrier(0);
    __builtin_amdgcn_s_setprio(1);
    #pragma unroll
    for (int tml = 0; tml < 4; tml++)
      #pragma unroll
      for (int tnl = 0; tnl < 2; tnl++) {
        acc[4+tml][2+tnl] = MFMA_BF16(af1[tml][0], bf[tnl][0], acc[4+tml][2+tnl], 0, 0, 0);
        acc[4+tml][2+tnl] = MFMA_BF16(af1[tml][1], bf[tnl][1], acc[4+tml][2+tnl], 0, 0, 0);
      }
    __builtin_amdgcn_s_setprio(0);
  }

  #pragma unroll
  for (int tm = 0; tm < 8; tm++) {
    const int ha = tm >> 2, tml = tm & 3;
    #pragma unroll
    for (int tn = 0; tn < 4; tn++) {
      const int hb = tn >> 1, tnl = tn & 1;
      const int n = n0 + hb * 128 + wn * 32 + tnl * 16 + col;
      const float bn = bias[n];
      #pragma unroll
      for (int r = 0; r < 4; r++) {
        const int m = m0 + ha * 128 + wm * 64 + tml * 16 + quad * 4 + r;
        float v = acc[tm][tn][r] + bn;
        if (EPI == EPI_QK) {
          int nl = n & 1023, h = nl >> 6, hd = nl & 63;
          int bb = m >> 11, s2 = m & 2047;
          if (n < 1024)
            ((ushort*)outp)[(((size_t)(bb * 16 + h) * 2048 + s2) * 64) + hd] = f2bf(v * scale);
          else
            ((ushort*)outp2)[(((size_t)(bb * 16 + h) * 2048 + s2) * 64) + hd] = f2bf(v);
        } else {  // EPI_GELU
          float u = v * 0.7978845608028654f * (1.0f + 0.044715f * v * v);
          float e = __builtin_amdgcn_exp2f(u * 2.885390081777927f);  // e^{2u}
          float th = 1.0f - 2.0f * __builtin_amdgcn_rcpf(e + 1.0f);
          ((ushort*)outp)[(size_t)m * N + n] = f2bf(0.5f * v * (1.0f + th));
        }
      }
    }
  }
}

// ------- 128x256 bf16 GEMM, BK=64, 8 waves, 2-phase counted pipeline, 1 barrier/phase --
// R10 gemmH with bottom barriers removed (same ledger as gemm256). 2 barriers/K-tile.
template <int EPI>
__global__ __launch_bounds__(512, 2) void gemmH_kernel(const ushort* __restrict__ A,
    const ushort* __restrict__ Bw, const float* __restrict__ bias,
    const float* __restrict__ res, void* __restrict__ outp, int K, int N, int gx) {
  __shared__ ushort As[2][128 * 64];   // 16 KB per buf
  __shared__ ushort Bs[2][256 * 64];   // 32 KB per buf
  const int t = threadIdx.x;
  const int lane = t & 63, wave = t >> 6;
  const int col = lane & 15, quad = lane >> 4;
  const int bl = (blockIdx.x & 7) * 32 + (blockIdx.x >> 3);   // XCD-chunked (grid=256)
  const int m0 = (bl % gx) * 128, n0 = (bl / gx) * 256;
  const int wm = wave >> 2, wn = wave & 3;   // 2 x 4; per-wave out 64 x 64

  f32x4 acc[4][4];   // [tml][hb*2+tnl]
  #pragma unroll
  for (int i = 0; i < 4; i++)
    #pragma unroll
    for (int j = 0; j < 4; j++)
      acc[i][j] = (f32x4){0.f, 0.f, 0.f, 0.f};

  size_t aoff[2], boff[2];
  int ad0[2], bd0[2];
  #pragma unroll
  for (int i = 0; i < 2; i++) {
    int c = i * 512 + t, r = c >> 3, p = c & 7;   // r in 0..127
    aoff[i] = (size_t)(m0 + r) * K + (p ^ (r & 7)) * 8;
    boff[i] = (size_t)(n0 + r) * K + (p ^ (r & 7)) * 8;
    ad0[i] = c * 8; bd0[i] = c * 8;
  }
  const size_t upB = (size_t)128 * K;   // B1 rows n0+128..255

  const int NT = K >> 6;
  // prologue: A, B0, B1 of tile 0; wait A,B0 (B1 in flight, covered by kt0's vmcnt(4))
  #pragma unroll
  for (int i = 0; i < 2; i++) async_cp16(A  + aoff[i],       &As[0][ad0[i]]);
  #pragma unroll
  for (int i = 0; i < 2; i++) async_cp16(Bw + boff[i],       &Bs[0][bd0[i]]);
  #pragma unroll
  for (int i = 0; i < 2; i++) async_cp16(Bw + boff[i] + upB, &Bs[0][8192 + bd0[i]]);
  asm volatile("s_waitcnt vmcnt(2)" ::: "memory");
  __builtin_amdgcn_sched_barrier(0);
  __builtin_amdgcn_s_barrier();
  __builtin_amdgcn_sched_barrier(0);

  short8 af[4][2], bf[2][2];
  for (int kt = 0; kt < NT; kt++) {
    const int cur = kt & 1, nxt = cur ^ 1;
    const size_t ko = (size_t)(kt + 1) << 6;
    const bool more = (kt + 1 < NT);

    // ---- ph0 (hb=0): read af (8) + bf(B0) (4); stage A(t+1), B0(t+1); vmcnt(4)
    #pragma unroll
    for (int tml = 0; tml < 4; tml++) {
      const int row = wm * 64 + tml * 16 + col;
      #pragma unroll
      for (int c = 0; c < 2; c++)
        af[tml][c] = *(const short8*)&As[cur][row * 64 + (((c * 4 + quad) ^ (row & 7)) * 8)];
    }
    #pragma unroll
    for (int tnl = 0; tnl < 2; tnl++) {
      const int row = wn * 32 + tnl * 16 + col;
      #pragma unroll
      for (int c = 0; c < 2; c++)
        bf[tnl][c] = *(const short8*)&Bs[cur][row * 64 + (((c * 4 + quad) ^ (row & 7)) * 8)];
    }
    if (more) {
      #pragma unroll
      for (int i = 0; i < 2; i++) async_cp16(A  + aoff[i] + ko, &As[nxt][ad0[i]]);
      #pragma unroll
      for (int i = 0; i < 2; i++) async_cp16(Bw + boff[i] + ko, &Bs[nxt][bd0[i]]);
      asm volatile("s_waitcnt vmcnt(4)" ::: "memory");
    } else {
      asm volatile("s_waitcnt vmcnt(0)" ::: "memory");
    }
    __builtin_amdgcn_sched_barrier(0);
    __builtin_amdgcn_s_barrier();
    asm volatile("s_waitcnt lgkmcnt(0)" ::: "memory");
    __builtin_amdgcn_sched_barrier(0);
    __builtin_amdgcn_s_setprio(1);
    #pragma unroll
    for (int tml = 0; tml < 4; tml++)
      #pragma unroll
      for (int tnl = 0; tnl < 2; tnl++) {
        acc[tml][tnl] = MFMA_BF16(af[tml][0], bf[tnl][0], acc[tml][tnl], 0, 0, 0);
        acc[tml][tnl] = MFMA_BF16(af[tml][1], bf[tnl][1], acc[tml][tnl], 0, 0, 0);
      }
    __builtin_amdgcn_s_setprio(0);

    // ---- ph1 (hb=1): read bf(B1); stage B1(t+1); vmcnt(2)
    #pragma unroll
    for (int tnl = 0; tnl < 2; tnl++) {
      const int rp = wn * 32 + tnl * 16 + col;   // row-in-unit; (128+rp)&7 == rp&7
      #pragma unroll
      for (int c = 0; c < 2; c++)
        bf[tnl][c] = *(const short8*)&Bs[cur][8192 + rp * 64 + (((c * 4 + quad) ^ (rp & 7)) * 8)];
    }
    if (more) {
      #pragma unroll
      for (int i = 0; i < 2; i++) async_cp16(Bw + boff[i] + upB + ko, &Bs[nxt][8192 + bd0[i]]);
      asm volatile("s_waitcnt vmcnt(2)" ::: "memory");
    } else {
      asm volatile("s_waitcnt vmcnt(0)" ::: "memory");
    }
    __builtin_amdgcn_sched_barrier(0);
    __builtin_amdgcn_s_barrier();
    asm volatile("s_waitcnt lgkmcnt(0)" ::: "memory");
    __builtin_amdgcn_sched_barrier(0);
    __builtin_amdgcn_s_setprio(1);
    #pragma unroll
    for (int tml = 0; tml < 4; tml++)
      #pragma unroll
      for (int tnl = 0; tnl < 2; tnl++) {
        acc[tml][2+tnl] = MFMA_BF16(af[tml][0], bf[tnl][0], acc[tml][2+tnl], 0, 0, 0);
        acc[tml][2+tnl] = MFMA_BF16(af[tml][1], bf[tnl][1], acc[tml][2+tnl], 0, 0, 0);
      }
    __builtin_amdgcn_s_setprio(0);
  }

  #pragma unroll
  for (int tml = 0; tml < 4; tml++) {
    #pragma unroll
    for (int tn = 0; tn < 4; tn++) {
      const int hb = tn >> 1, tnl = tn & 1;
      const int n = n0 + hb * 128 + wn * 32 + tnl * 16 + col;
      #pragma unroll
      for (int r = 0; r < 4; r++) {
        const int m = m0 + wm * 64 + tml * 16 + quad * 4 + r;
        float v = acc[tml][tn][r];
        if (EPI == EPI_VT) {
          // A=Wv (m = v-dim), Bw=xn (n = token); bias indexed by m
          float vv = v + bias[m];
          int h = m >> 6, hd = m & 63, bb = n >> 11, s2 = n & 2047;
          ((ushort*)outp)[((size_t)((bb * 16 + h) * 64 + hd)) * 2048 + s2] = f2bf(vv);
        } else {  // EPI_WO / EPI_OUT: float out + bias + residual
          ((float*)outp)[(size_t)m * N + n] = v + bias[n] + res[(size_t)m * N + n];
        }
      }
    }
  }
}

// ---------------- flash attention v14: 8-wave blocks, zero-tail grid ----------
// 512 blocks = 64 heads x 8 q-tiles(256) = exactly 2 blocks/CU (no tail).
// 8 waves x 32 q; K/V staging role-split: waves 0-3 stage K halves, waves 4-7 stage V
// (coverage identical to v13, 2 asyncs/wave). LDS = Ks 16 + Vs 16 + P[8] 16 = 48 KB.
// Inner loop identical to v13 (l-sum via ones-MFMA).
__global__ __launch_bounds__(512) void attn_kernel(const ushort* __restrict__ Qb,
    const ushort* __restrict__ Kb, const ushort* __restrict__ Vt,
    ushort* __restrict__ ctx) {
  const int lane = threadIdx.x & 63, wave = threadIdx.x >> 6;   // 0..7
  const int col = lane & 15, quad = lane >> 4;
  const int bx = blockIdx.x;
  const int bh = bx & 63;          // XCD = bh % 8 for every q-tile of this head
  const int qt = bx >> 6;          // 0..7
  const int qbase = qt * 256 + wave * 32;
  const ushort* Qh = Qb + (size_t)bh * 2048 * 64;
  const ushort* Kh = Kb + (size_t)bh * 2048 * 64;
  const ushort* Vh = Vt + (size_t)bh * 64 * 2048;

  short8 qa[2][2];
  #pragma unroll
  for (int qg = 0; qg < 2; qg++) {
    const ushort* Qr = Qh + (size_t)(qbase + qg * 16 + col) * 64 + quad * 8;
    qa[qg][0] = *(const short8*)Qr;
    qa[qg][1] = *(const short8*)(Qr + 32);
  }

  short8 ones8;
  #pragma unroll
  for (int i = 0; i < 8; i++) ones8[i] = (short)0x3F80;   // 1.0 bf16

  f32x4 Ot[2][4], Ol[2];
  #pragma unroll
  for (int qg = 0; qg < 2; qg++) {
    Ol[qg] = (f32x4){0.f, 0.f, 0.f, 0.f};
    #pragma unroll
    for (int dt = 0; dt < 4; dt++) Ot[qg][dt] = (f32x4){0.f, 0.f, 0.f, 0.f};
  }

  __shared__ ushort Ks[2][2][64 * 32];   // [buf][d-half][key*32 + swz-chunk] 16 KB
  __shared__ ushort Vs[2][2][64 * 32];   // [buf][key-half][d*32 + swz-chunk] 16 KB
  __shared__ ushort P_lds[8][16][64];    // [wave][q][8 x 16B chunks, swz] 16 KB

  const int lrow = lane >> 2;
  const int sw = wave & 3;
  const int srow = sw * 16 + lrow;                         // row this lane stages
  const int lcol = ((lane & 3) ^ ((srow >> 1) & 3)) * 8;   // swizzled 16B chunk in 64B half
  const ushort* Kg = Kh + (size_t)srow * 64 + lcol;        // + kb*64 (+32 for half 1)
  const ushort* Vg = Vh + (size_t)srow * 2048 + lcol;      // + kb   (+32 for half 1)
  const int so = (sw * 16) * 32;
  const bool kRole = (wave < 4);

  const int kvswz = (col >> 1) & 3;   // fragment-read XOR (rows kt*16+col: (row>>1)&3)
  const int pswz = col & 7;           // P chunk XOR

  // prologue: stage chunk 0 into buf 0 (role-split)
  if (kRole) {
    async_cp16(Kg,      &Ks[0][0][so]);
    async_cp16(Kg + 32, &Ks[0][1][so]);
  } else {
    async_cp16(Vg,      &Vs[0][0][so]);
    async_cp16(Vg + 32, &Vs[0][1][so]);
  }
  __syncthreads();

  int cur = 0;
  for (int kb = 0; kb < 2048; kb += 64) {
    if (kb + 64 < 2048) {
      const int nxt = cur ^ 1;
      if (kRole) {
        async_cp16(Kg + (size_t)(kb + 64) * 64,      &Ks[nxt][0][so]);
        async_cp16(Kg + (size_t)(kb + 64) * 64 + 32, &Ks[nxt][1][so]);
      } else {
        async_cp16(Vg + (kb + 64),                   &Vs[nxt][0][so]);
        async_cp16(Vg + (kb + 64) + 32,              &Vs[nxt][1][so]);
      }
    }

    // fragments from LDS (shared across the 2 q-groups), swizzled reads
    short8 kf[4][2], vf[4][2];
    #pragma unroll
    for (int kt = 0; kt < 4; kt++)
      #pragma unroll
      for (int c = 0; c < 2; c++)
        kf[kt][c] = *(const short8*)&Ks[cur][c][(kt * 16 + col) * 32 + (quad ^ kvswz) * 8];
    #pragma unroll
    for (int dt = 0; dt < 4; dt++)
      #pragma unroll
      for (int c = 0; c < 2; c++)
        vf[dt][c] = *(const short8*)&Vs[cur][c][(dt * 16 + col) * 32 + (quad ^ kvswz) * 8];

    #pragma unroll
    for (int qg = 0; qg < 2; qg++) {
      f32x4 s[4];
      __builtin_amdgcn_s_setprio(1);
      #pragma unroll
      for (int kt = 0; kt < 4; kt++) {
        s[kt] = (f32x4){0.f, 0.f, 0.f, 0.f};
        s[kt] = MFMA_BF16(kf[kt][0], qa[qg][0], s[kt], 0, 0, 0);
        s[kt] = MFMA_BF16(kf[kt][1], qa[qg][1], s[kt], 0, 0, 0);
      }
      __builtin_amdgcn_s_setprio(0);
      ushort(*P)[64] = P_lds[wave];
      #pragma unroll
      for (int kt = 0; kt < 4; kt++) {
        float p0 = __builtin_amdgcn_exp2f(s[kt][0]);
        float p1 = __builtin_amdgcn_exp2f(s[kt][1]);
        float p2 = __builtin_amdgcn_exp2f(s[kt][2]);
        float p3 = __builtin_amdgcn_exp2f(s[kt][3]);
        uint2 pk;
        asm("v_cvt_pk_bf16_f32 %0, %1, %2" : "=v"(pk.x) : "v"(p0), "v"(p1));
        asm("v_cvt_pk_bf16_f32 %0, %1, %2" : "=v"(pk.y) : "v"(p2), "v"(p3));
        *(uint2*)&P[col][(((2 * kt + (quad >> 1)) ^ pswz) * 8) + (quad & 1) * 4] = pk;
      }
      // PV for this qg (same-wave LDS RAW handled in-order; no barrier needed)
      #pragma unroll
      for (int c = 0; c < 2; c++) {
        short8 pf = *(const short8*)&P_lds[wave][col][((4 * c + quad) ^ pswz) * 8];
        __builtin_amdgcn_s_setprio(1);
        #pragma unroll
        for (int dt = 0; dt < 4; dt++)
          Ot[qg][dt] = MFMA_BF16(vf[dt][c], pf, Ot[qg][dt], 0, 0, 0);
        Ol[qg] = MFMA_BF16(ones8, pf, Ol[qg], 0, 0, 0);   // l-sum on MFMA pipe
        __builtin_amdgcn_s_setprio(0);
      }
    }
    __syncthreads();
    cur ^= 1;
  }

  const int bb = bh >> 4, h = bh & 15;
  #pragma unroll
  for (int qg = 0; qg < 2; qg++) {
    float inv = __builtin_amdgcn_rcpf(Ol[qg][0]);   // identical in all lanes/regs
    const int q = qbase + qg * 16 + col;
    size_t base = ((size_t)(bb * 2048 + q)) * 1024 + h * 64;
    #pragma unroll
    for (int dt = 0; dt < 4; dt++) {
      ushort4 o;
      o.x = f2bf(Ot[qg][dt][0] * inv);
      o.y = f2bf(Ot[qg][dt][1] * inv);
      o.z = f2bf(Ot[qg][dt][2] * inv);
      o.w = f2bf(Ot[qg][dt][3] * inv);
      *(ushort4*)&ctx[base + dt * 16 + quad * 4] = o;
    }
  }
}

// ---------------- host ----------------
extern "C" void kernel_launch(void* const* d_in, const int* in_sizes, int n_in,
                              void* d_out, int out_size, void* d_ws, size_t ws_size,
                              hipStream_t stream) {
  const float* x     = (const float*)d_in[0];
  const float* Wq    = (const float*)d_in[1];
  const float* bq    = (const float*)d_in[2];
  const float* Wk    = (const float*)d_in[3];
  const float* bk    = (const float*)d_in[4];
  const float* Wv    = (const float*)d_in[5];
  const float* bv    = (const float*)d_in[6];
  const float* Wo    = (const float*)d_in[7];
  const float* bo    = (const float*)d_in[8];
  const float* W1    = (const float*)d_in[9];
  const float* b1    = (const float*)d_in[10];
  const float* W2    = (const float*)d_in[11];
  const float* b2    = (const float*)d_in[12];
  const float* ln1_g = (const float*)d_in[13];
  const float* ln1_b = (const float*)d_in[14];
  const float* ln2_g = (const float*)d_in[15];
  const float* ln2_b = (const float*)d_in[16];

  const size_t MB = 1ull << 20;
  char* ws = (char*)d_ws;
  ushort* Wqkv_b = (ushort*)(ws + 0 * MB);    // 6 MB  [3072,1024] (Q|K|V)
  ushort* Wo_b   = (ushort*)(ws + 6 * MB);    // 2 MB
  ushort* W1_b   = (ushort*)(ws + 8 * MB);    // 8 MB
  ushort* W2_b   = (ushort*)(ws + 16 * MB);   // 8 MB
  ushort* xn1    = (ushort*)(ws + 24 * MB);   // 16 MB
  ushort* Qb     = (ushort*)(ws + 40 * MB);   // 16 MB
  ushort* Kb     = (ushort*)(ws + 56 * MB);   // 16 MB
  ushort* Vt     = (ushort*)(ws + 72 * MB);   // 16 MB
  ushort* ctxb   = (ushort*)(ws + 88 * MB);   // 16 MB
  float*  x2     = (float*)(ws + 104 * MB);   // 32 MB
  ushort* xn2    = (ushort*)(ws + 136 * MB);  // 16 MB
  ushort* y1     = (ushort*)(ws + 152 * MB);  // 64 MB -> end 216 MB
  // bqkv aliases start of y1 (lifetime-disjoint: consumed before GELU GEMM writes y1)
  float*  bqkv   = (float*)(ws + 152 * MB);

  conv_all<<<12291, 256, 0, stream>>>(Wq, Wk, Wv, Wo, W1, W2, bq, bk, bv,
                                      Wqkv_b, Wo_b, W1_b, W2_b, bqkv);

  ln_kernel<<<8192, 256, 0, stream>>>(x, ln1_g, ln1_b, xn1);

  const float cs = 0.125f * 1.4426950408889634f;  // log2(e)/sqrt(64), folded into Q
  // Q|K projections (N=2048): 256^2 4-phase pipeline (hoisted frags, 1 barrier/phase)
  gemm256_kernel<EPI_QK><<<dim3(32, 8), 512, 0, stream>>>(
      xn1, Wqkv_b, bqkv, Qb, Kb, 1024, 2048, cs);
  // V^T projection: A = Wv (rows = v-dim), B = xn (rows = tokens) -> C[vdim, token]
  gemmH_kernel<EPI_VT><<<256, 512, 0, stream>>>(
      Wqkv_b + (size_t)2048 * 1024, xn1, bqkv + 2048, nullptr, Vt, 1024, 8192, 8);

  attn_kernel<<<512, 512, 0, stream>>>(Qb, Kb, Vt, ctxb);

  gemmH_kernel<EPI_WO><<<256, 512, 0, stream>>>(
      ctxb, Wo_b, bo, x, x2, 1024, 1024, 64);

  ln_kernel<<<8192, 256, 0, stream>>>(x2, ln2_g, ln2_b, xn2);

  gemm256_kernel<EPI_GELU><<<dim3(32, 16), 512, 0, stream>>>(
      xn2, W1_b, b1, y1, nullptr, 1024, 4096, 1.0f);
  gemmH_kernel<EPI_OUT><<<256, 512, 0, stream>>>(
      y1, W2_b, b2, x2, d_out, 4096, 1024, 64);
}

// Round 12
// 457.533 us; speedup vs baseline: 1.1335x; 1.0545x over previous
//
#include <hip/hip_runtime.h>
#include <hip/hip_bf16.h>
#include <math.h>

typedef __attribute__((ext_vector_type(8))) short short8;
typedef __attribute__((ext_vector_type(4))) float f32x4;

#define MFMA_BF16 __builtin_amdgcn_mfma_f32_16x16x32_bf16

__device__ __forceinline__ ushort f2bf(float f) {
  union { __hip_bfloat16 h; ushort u; } c;
  c.h = __float2bfloat16(f);
  return c.u;
}
__device__ __forceinline__ void async_cp16(const ushort* g, ushort* l) {
  __builtin_amdgcn_global_load_lds(
      (const __attribute__((address_space(1))) void*)g,
      (__attribute__((address_space(3))) void*)l, 16, 0, 0);
}

// ------------- fused weight fp32->bf16 conversion + bias concat (one launch) -------------
__global__ __launch_bounds__(256) void conv_all(
    const float* __restrict__ Wq, const float* __restrict__ Wk,
    const float* __restrict__ Wv, const float* __restrict__ Wo,
    const float* __restrict__ W1, const float* __restrict__ W2,
    const float* __restrict__ bq, const float* __restrict__ bk,
    const float* __restrict__ bv,
    ushort* __restrict__ wqkv, ushort* __restrict__ wo,
    ushort* __restrict__ w1, ushort* __restrict__ w2,
    float* __restrict__ bqkv) {
  int i = blockIdx.x * 256 + threadIdx.x;   // float4 index
  if (i < 3145728) {
    const float* src; ushort* dst; int off;
    if (i < 786432)        { // Wq|Wk|Wv -> concatenated wqkv [3072,1024]
      dst = wqkv; off = i;
      if (i < 262144)      src = Wq + (size_t)i * 4;
      else if (i < 524288) src = Wk + (size_t)(i - 262144) * 4;
      else                 src = Wv + (size_t)(i - 524288) * 4;
    } else if (i < 1048576) { dst = wo; off = i - 786432;  src = Wo + (size_t)off * 4; }
    else if (i < 2097152)   { dst = w1; off = i - 1048576; src = W1 + (size_t)off * 4; }
    else                    { dst = w2; off = i - 2097152; src = W2 + (size_t)off * 4; }
    float4 v = *(const float4*)src;
    ushort4 o;
    o.x = f2bf(v.x); o.y = f2bf(v.y); o.z = f2bf(v.z); o.w = f2bf(v.w);
    ((ushort4*)dst)[off] = o;
  } else if (i < 3146496) {  // biases: 3 x 256 float4
    int off = i - 3145728;
    const float* src;
    if (off < 256)      src = bq + (size_t)off * 4;
    else if (off < 512) src = bk + (size_t)(off - 256) * 4;
    else                src = bv + (size_t)(off - 512) * 4;
    ((float4*)bqkv)[off] = *(const float4*)src;
  }
}

// ---------------- layernorm: one block per 1024-float row -> bf16 ----------------
__global__ __launch_bounds__(256) void ln_kernel(const float* __restrict__ x,
    const float* __restrict__ g, const float* __restrict__ b,
    ushort* __restrict__ out) {
  const int row = blockIdx.x, t = threadIdx.x;
  float4 v = ((const float4*)(x + (size_t)row * 1024))[t];
  float s  = v.x + v.y + v.z + v.w;
  float ss = v.x*v.x + v.y*v.y + v.z*v.z + v.w*v.w;
  #pragma unroll
  for (int off = 32; off >= 1; off >>= 1) {
    s  += __shfl_xor(s, off);
    ss += __shfl_xor(ss, off);
  }
  __shared__ float red[8];
  int wv = t >> 6, ln = t & 63;
  if (ln == 0) { red[wv] = s; red[4 + wv] = ss; }
  __syncthreads();
  float S  = red[0] + red[1] + red[2] + red[3];
  float SS = red[4] + red[5] + red[6] + red[7];
  float mu  = S * (1.0f/1024.0f);
  float var = SS * (1.0f/1024.0f) - mu*mu;
  float rs  = rsqrtf(var + 1e-6f);
  float4 gv = ((const float4*)g)[t];
  float4 bv = ((const float4*)b)[t];
  ushort4 o;
  o.x = f2bf((v.x-mu)*rs*gv.x + bv.x);
  o.y = f2bf((v.y-mu)*rs*gv.y + bv.y);
  o.z = f2bf((v.z-mu)*rs*gv.z + bv.z);
  o.w = f2bf((v.w-mu)*rs*gv.w + bv.w);
  ((ushort4*)(out + (size_t)row*1024))[t] = o;
}

enum { EPI_QK = 0, EPI_VT = 1, EPI_WO = 2, EPI_GELU = 3, EPI_OUT = 4 };

// ------- 256x256 bf16 GEMM, BK=64, 8 waves, 4-phase pipeline, ONE barrier/phase -------
template <int EPI>
__global__ __launch_bounds__(512, 2) void gemm256_kernel(const ushort* __restrict__ A,
    const ushort* __restrict__ Bw, const float* __restrict__ bias,
    void* __restrict__ outp, void* __restrict__ outp2, int K, int N, float scale) {
  __shared__ ushort As[2][256 * 64];   // 32 KB per buf
  __shared__ ushort Bs[2][256 * 64];
  const int t = threadIdx.x;
  const int lane = t & 63, wave = t >> 6;
  const int col = lane & 15, quad = lane >> 4;
  const int m0 = blockIdx.x * 256, n0 = blockIdx.y * 256;
  const int wm = wave >> 2, wn = wave & 3;   // 2 x 4

  f32x4 acc[8][4];
  #pragma unroll
  for (int i = 0; i < 8; i++)
    #pragma unroll
    for (int j = 0; j < 4; j++)
      acc[i][j] = (f32x4){0.f, 0.f, 0.f, 0.f};

  size_t aoff[2], boff[2];
  int d0[2];
  #pragma unroll
  for (int i = 0; i < 2; i++) {
    int c = i * 512 + t, r = c >> 3, p = c & 7;
    aoff[i] = (size_t)(m0 + r) * K + (p ^ (r & 7)) * 8;
    boff[i] = (size_t)(n0 + r) * K + (p ^ (r & 7)) * 8;
    d0[i] = c * 8;
  }
  const size_t up = (size_t)128 * K;

  const int NT = K >> 6;
  // prologue: tile 0, order A0,B0,A1,B1; wait A0,B0 (A1,B1 in flight)
  #pragma unroll
  for (int i = 0; i < 2; i++) async_cp16(A  + aoff[i],      &As[0][d0[i]]);
  #pragma unroll
  for (int i = 0; i < 2; i++) async_cp16(Bw + boff[i],      &Bs[0][d0[i]]);
  #pragma unroll
  for (int i = 0; i < 2; i++) async_cp16(A  + aoff[i] + up, &As[0][8192 + d0[i]]);
  #pragma unroll
  for (int i = 0; i < 2; i++) async_cp16(Bw + boff[i] + up, &Bs[0][8192 + d0[i]]);
  asm volatile("s_waitcnt vmcnt(4)" ::: "memory");
  __builtin_amdgcn_sched_barrier(0);
  __builtin_amdgcn_s_barrier();
  __builtin_amdgcn_sched_barrier(0);

  short8 af0[4][2], af1[4][2], bf[2][2];
  for (int kt = 0; kt < NT; kt++) {
    const int cur = kt & 1, nxt = cur ^ 1;
    const size_t ko = (size_t)(kt + 1) << 6;
    const bool more = (kt + 1 < NT);

    // ---- ph0: read af0 + bf(B0); stage A0(t+1); vmcnt(4); barrier; MFMA quad (0,0)
    #pragma unroll
    for (int tml = 0; tml < 4; tml++) {
      const int row = wm * 64 + tml * 16 + col;
      #pragma unroll
      for (int c = 0; c < 2; c++)
        af0[tml][c] = *(const short8*)&As[cur][row * 64 + (((c * 4 + quad) ^ (row & 7)) * 8)];
    }
    #pragma unroll
    for (int tnl = 0; tnl < 2; tnl++) {
      const int row = wn * 32 + tnl * 16 + col;
      #pragma unroll
      for (int c = 0; c < 2; c++)
        bf[tnl][c] = *(const short8*)&Bs[cur][row * 64 + (((c * 4 + quad) ^ (row & 7)) * 8)];
    }
    if (more) {
      #pragma unroll
      for (int i = 0; i < 2; i++) async_cp16(A + aoff[i] + ko, &As[nxt][d0[i]]);
      asm volatile("s_waitcnt vmcnt(4)" ::: "memory");
    } else {
      asm volatile("s_waitcnt vmcnt(2)" ::: "memory");
    }
    __builtin_amdgcn_sched_barrier(0);
    __builtin_amdgcn_s_barrier();
    asm volatile("s_waitcnt lgkmcnt(0)" ::: "memory");
    __builtin_amdgcn_sched_barrier(0);
    __builtin_amdgcn_s_setprio(1);
    #pragma unroll
    for (int tml = 0; tml < 4; tml++)
      #pragma unroll
      for (int tnl = 0; tnl < 2; tnl++) {
        acc[tml][tnl] = MFMA_BF16(af0[tml][0], bf[tnl][0], acc[tml][tnl], 0, 0, 0);
        acc[tml][tnl] = MFMA_BF16(af0[tml][1], bf[tnl][1], acc[tml][tnl], 0, 0, 0);
      }
    __builtin_amdgcn_s_setprio(0);

    // ---- ph1: read af1; stage B0(t+1); vmcnt(4); barrier; MFMA quad (1,0)
    #pragma unroll
    for (int tml = 0; tml < 4; tml++) {
      const int row = 128 + wm * 64 + tml * 16 + col;
      #pragma unroll
      for (int c = 0; c < 2; c++)
        af1[tml][c] = *(const short8*)&As[cur][row * 64 + (((c * 4 + quad) ^ (row & 7)) * 8)];
    }
    if (more) {
      #pragma unroll
      for (int i = 0; i < 2; i++) async_cp16(Bw + boff[i] + ko, &Bs[nxt][d0[i]]);
      asm volatile("s_waitcnt vmcnt(4)" ::: "memory");
    } else {
      asm volatile("s_waitcnt vmcnt(0)" ::: "memory");
    }
    __builtin_amdgcn_sched_barrier(0);
    __builtin_amdgcn_s_barrier();
    asm volatile("s_waitcnt lgkmcnt(0)" ::: "memory");
    __builtin_amdgcn_sched_barrier(0);
    __builtin_amdgcn_s_setprio(1);
    #pragma unroll
    for (int tml = 0; tml < 4; tml++)
      #pragma unroll
      for (int tnl = 0; tnl < 2; tnl++) {
        acc[4+tml][tnl] = MFMA_BF16(af1[tml][0], bf[tnl][0], acc[4+tml][tnl], 0, 0, 0);
        acc[4+tml][tnl] = MFMA_BF16(af1[tml][1], bf[tnl][1], acc[4+tml][tnl], 0, 0, 0);
      }
    __builtin_amdgcn_s_setprio(0);

    // ---- ph2: read bf(B1) (overwrite); stage A1(t+1); vmcnt(4); barrier; quad (0,1)
    #pragma unroll
    for (int tnl = 0; tnl < 2; tnl++) {
      const int row = 128 + wn * 32 + tnl * 16 + col;
      #pragma unroll
      for (int c = 0; c < 2; c++)
        bf[tnl][c] = *(const short8*)&Bs[cur][row * 64 + (((c * 4 + quad) ^ (row & 7)) * 8)];
    }
    if (more) {
      #pragma unroll
      for (int i = 0; i < 2; i++) async_cp16(A + aoff[i] + up + ko, &As[nxt][8192 + d0[i]]);
      asm volatile("s_waitcnt vmcnt(4)" ::: "memory");
    } else {
      asm volatile("s_waitcnt vmcnt(0)" ::: "memory");
    }
    __builtin_amdgcn_sched_barrier(0);
    __builtin_amdgcn_s_barrier();
    asm volatile("s_waitcnt lgkmcnt(0)" ::: "memory");
    __builtin_amdgcn_sched_barrier(0);
    __builtin_amdgcn_s_setprio(1);
    #pragma unroll
    for (int tml = 0; tml < 4; tml++)
      #pragma unroll
      for (int tnl = 0; tnl < 2; tnl++) {
        acc[tml][2+tnl] = MFMA_BF16(af0[tml][0], bf[tnl][0], acc[tml][2+tnl], 0, 0, 0);
        acc[tml][2+tnl] = MFMA_BF16(af0[tml][1], bf[tnl][1], acc[tml][2+tnl], 0, 0, 0);
      }
    __builtin_amdgcn_s_setprio(0);

    // ---- ph3: no reads; stage B1(t+1); vmcnt(4); barrier; MFMA quad (1,1)
    if (more) {
      #pragma unroll
      for (int i = 0; i < 2; i++) async_cp16(Bw + boff[i] + up + ko, &Bs[nxt][8192 + d0[i]]);
      asm volatile("s_waitcnt vmcnt(4)" ::: "memory");
    } else {
      asm volatile("s_waitcnt vmcnt(0)" ::: "memory");
    }
    __builtin_amdgcn_sched_barrier(0);
    __builtin_amdgcn_s_barrier();
    asm volatile("s_waitcnt lgkmcnt(0)" ::: "memory");
    __builtin_amdgcn_sched_barrier(0);
    __builtin_amdgcn_s_setprio(1);
    #pragma unroll
    for (int tml = 0; tml < 4; tml++)
      #pragma unroll
      for (int tnl = 0; tnl < 2; tnl++) {
        acc[4+tml][2+tnl] = MFMA_BF16(af1[tml][0], bf[tnl][0], acc[4+tml][2+tnl], 0, 0, 0);
        acc[4+tml][2+tnl] = MFMA_BF16(af1[tml][1], bf[tnl][1], acc[4+tml][2+tnl], 0, 0, 0);
      }
    __builtin_amdgcn_s_setprio(0);
  }

  #pragma unroll
  for (int tm = 0; tm < 8; tm++) {
    const int ha = tm >> 2, tml = tm & 3;
    #pragma unroll
    for (int tn = 0; tn < 4; tn++) {
      const int hb = tn >> 1, tnl = tn & 1;
      const int n = n0 + hb * 128 + wn * 32 + tnl * 16 + col;
      const float bn = bias[n];
      #pragma unroll
      for (int r = 0; r < 4; r++) {
        const int m = m0 + ha * 128 + wm * 64 + tml * 16 + quad * 4 + r;
        float v = acc[tm][tn][r] + bn;
        if (EPI == EPI_QK) {
          int nl = n & 1023, h = nl >> 6, hd = nl & 63;
          int bb = m >> 11, s2 = m & 2047;
          if (n < 1024)
            ((ushort*)outp)[(((size_t)(bb * 16 + h) * 2048 + s2) * 64) + hd] = f2bf(v * scale);
          else
            ((ushort*)outp2)[(((size_t)(bb * 16 + h) * 2048 + s2) * 64) + hd] = f2bf(v);
        } else {  // EPI_GELU
          float u = v * 0.7978845608028654f * (1.0f + 0.044715f * v * v);
          float e = __builtin_amdgcn_exp2f(u * 2.885390081777927f);  // e^{2u}
          float th = 1.0f - 2.0f * __builtin_amdgcn_rcpf(e + 1.0f);
          ((ushort*)outp)[(size_t)m * N + n] = f2bf(0.5f * v * (1.0f + th));
        }
      }
    }
  }
}

// ------- 128x128 bf16 GEMM, BK=64, 4 waves, 2-phase counted pipeline (VT/WO/OUT) -------
// LDS 64 KB -> TWO blocks/CU (independent barrier groups fill each other's stalls —
// the R11 attn-v14 mechanism applied to GEMM). Grid exactly 512 blocks = 2/CU, zero
// tail for all three shapes. 16 MFMA/phase/wave (R9 phase-mass lesson).
// Stage units/K-tile: A (128x64, 4 loads/thr), B0 (n-rows 0-63, 2), B1 (64-127, 2).
// Per-thread vmcnt ledger (queue-simulated): prologue stage A,B0,B1 -> vmcnt(2)
// (drains A,B0; B1 in flight); ph0 stages A,B0(t+1) -> vmcnt(6) (drains B1(t), read
// in ph1); ph1 stages B1(t+1) -> vmcnt(2) (drains A,B0(t+1), read next ph0). Tails
// 0/0. Distance-1 prefetch into buf[(t+1)&1] != read buf (WAR clean). Same row&7
// chunk-XOR swizzle (128-B rows, 0-conflict measured). Grid decode: same-A-panel
// blocks contiguous within an XCD (A-panel L2 reuse).
template <int EPI>
__global__ __launch_bounds__(256, 2) void gemmP_kernel(const ushort* __restrict__ A,
    const ushort* __restrict__ Bw, const float* __restrict__ bias,
    const float* __restrict__ res, void* __restrict__ outp, int K, int N, int gn) {
  __shared__ ushort As[2][128 * 64];   // 16 KB per buf
  __shared__ ushort Bs[2][128 * 64];   // 16 KB per buf (B0 @0, B1 @4096)
  const int t = threadIdx.x;
  const int lane = t & 63, wave = t >> 6;   // 0..3
  const int col = lane & 15, quad = lane >> 4;
  const int bl = (blockIdx.x & 7) * 64 + (blockIdx.x >> 3);   // XCD-chunked (grid=512)
  const int m0 = (bl / gn) * 128, n0 = (bl % gn) * 128;
  const int wm = wave >> 1, wn = wave & 1;   // 2 x 2; per-wave out 64 x 64

  f32x4 acc[4][4];   // [tml][hb*2+tnl]
  #pragma unroll
  for (int i = 0; i < 4; i++)
    #pragma unroll
    for (int j = 0; j < 4; j++)
      acc[i][j] = (f32x4){0.f, 0.f, 0.f, 0.f};

  // A: 1024 chunks -> 4/thread. B0/B1: 512 chunks each -> 2/thread.
  size_t aoff[4]; int ad0[4];
  #pragma unroll
  for (int i = 0; i < 4; i++) {
    int c = i * 256 + t, r = c >> 3, p = c & 7;   // r in 0..127
    aoff[i] = (size_t)(m0 + r) * K + (p ^ (r & 7)) * 8;
    ad0[i] = c * 8;
  }
  size_t b0off[2]; int bd0[2];
  #pragma unroll
  for (int i = 0; i < 2; i++) {
    int c = i * 256 + t, r = c >> 3, p = c & 7;   // r in 0..63
    b0off[i] = (size_t)(n0 + r) * K + (p ^ (r & 7)) * 8;
    bd0[i] = c * 8;
  }
  const size_t upB = (size_t)64 * K;   // B1 rows n0+64..127

  const int NT = K >> 6;
  // prologue: stage A(0), B0(0), B1(0); vmcnt(2) (A,B0 landed; B1 in flight)
  #pragma unroll
  for (int i = 0; i < 4; i++) async_cp16(A  + aoff[i],        &As[0][ad0[i]]);
  #pragma unroll
  for (int i = 0; i < 2; i++) async_cp16(Bw + b0off[i],       &Bs[0][bd0[i]]);
  #pragma unroll
  for (int i = 0; i < 2; i++) async_cp16(Bw + b0off[i] + upB, &Bs[0][4096 + bd0[i]]);
  asm volatile("s_waitcnt vmcnt(2)" ::: "memory");
  __builtin_amdgcn_sched_barrier(0);
  __builtin_amdgcn_s_barrier();
  __builtin_amdgcn_sched_barrier(0);

  short8 af[4][2], bf[2][2];
  for (int kt = 0; kt < NT; kt++) {
    const int cur = kt & 1, nxt = cur ^ 1;
    const size_t ko = (size_t)(kt + 1) << 6;
    const bool more = (kt + 1 < NT);

    // ---- ph0 (hb=0): read af(8) + bf(B0)(4); stage A(t+1),B0(t+1); vmcnt(6)
    #pragma unroll
    for (int tml = 0; tml < 4; tml++) {
      const int row = wm * 64 + tml * 16 + col;
      #pragma unroll
      for (int c = 0; c < 2; c++)
        af[tml][c] = *(const short8*)&As[cur][row * 64 + (((c * 4 + quad) ^ (row & 7)) * 8)];
    }
    #pragma unroll
    for (int tnl = 0; tnl < 2; tnl++) {
      const int row = wn * 32 + tnl * 16 + col;
      #pragma unroll
      for (int c = 0; c < 2; c++)
        bf[tnl][c] = *(const short8*)&Bs[cur][row * 64 + (((c * 4 + quad) ^ (row & 7)) * 8)];
    }
    if (more) {
      #pragma unroll
      for (int i = 0; i < 4; i++) async_cp16(A  + aoff[i] + ko,  &As[nxt][ad0[i]]);
      #pragma unroll
      for (int i = 0; i < 2; i++) async_cp16(Bw + b0off[i] + ko, &Bs[nxt][bd0[i]]);
      asm volatile("s_waitcnt vmcnt(6)" ::: "memory");
    } else {
      asm volatile("s_waitcnt vmcnt(0)" ::: "memory");
    }
    __builtin_amdgcn_sched_barrier(0);
    __builtin_amdgcn_s_barrier();
    asm volatile("s_waitcnt lgkmcnt(0)" ::: "memory");
    __builtin_amdgcn_sched_barrier(0);
    __builtin_amdgcn_s_setprio(1);
    #pragma unroll
    for (int tml = 0; tml < 4; tml++)
      #pragma unroll
      for (int tnl = 0; tnl < 2; tnl++) {
        acc[tml][tnl] = MFMA_BF16(af[tml][0], bf[tnl][0], acc[tml][tnl], 0, 0, 0);
        acc[tml][tnl] = MFMA_BF16(af[tml][1], bf[tnl][1], acc[tml][tnl], 0, 0, 0);
      }
    __builtin_amdgcn_s_setprio(0);

    // ---- ph1 (hb=1): read bf(B1); stage B1(t+1); vmcnt(2)
    #pragma unroll
    for (int tnl = 0; tnl < 2; tnl++) {
      const int rp = wn * 32 + tnl * 16 + col;   // row-in-unit; (64+rp)&7 == rp&7
      #pragma unroll
      for (int c = 0; c < 2; c++)
        bf[tnl][c] = *(const short8*)&Bs[cur][4096 + rp * 64 + (((c * 4 + quad) ^ (rp & 7)) * 8)];
    }
    if (more) {
      #pragma unroll
      for (int i = 0; i < 2; i++) async_cp16(Bw + b0off[i] + upB + ko, &Bs[nxt][4096 + bd0[i]]);
      asm volatile("s_waitcnt vmcnt(2)" ::: "memory");
    } else {
      asm volatile("s_waitcnt vmcnt(0)" ::: "memory");
    }
    __builtin_amdgcn_sched_barrier(0);
    __builtin_amdgcn_s_barrier();
    asm volatile("s_waitcnt lgkmcnt(0)" ::: "memory");
    __builtin_amdgcn_sched_barrier(0);
    __builtin_amdgcn_s_setprio(1);
    #pragma unroll
    for (int tml = 0; tml < 4; tml++)
      #pragma unroll
      for (int tnl = 0; tnl < 2; tnl++) {
        acc[tml][2+tnl] = MFMA_BF16(af[tml][0], bf[tnl][0], acc[tml][2+tnl], 0, 0, 0);
        acc[tml][2+tnl] = MFMA_BF16(af[tml][1], bf[tnl][1], acc[tml][2+tnl], 0, 0, 0);
      }
    __builtin_amdgcn_s_setprio(0);
  }

  #pragma unroll
  for (int tml = 0; tml < 4; tml++) {
    #pragma unroll
    for (int tn = 0; tn < 4; tn++) {
      const int hb = tn >> 1, tnl = tn & 1;
      const int n = n0 + hb * 64 + wn * 32 + tnl * 16 + col;
      #pragma unroll
      for (int r = 0; r < 4; r++) {
        const int m = m0 + wm * 64 + tml * 16 + quad * 4 + r;
        float v = acc[tml][tn][r];
        if (EPI == EPI_VT) {
          // A=Wv (m = v-dim), Bw=xn (n = token); bias indexed by m
          float vv = v + bias[m];
          int h = m >> 6, hd = m & 63, bb = n >> 11, s2 = n & 2047;
          ((ushort*)outp)[((size_t)((bb * 16 + h) * 64 + hd)) * 2048 + s2] = f2bf(vv);
        } else {  // EPI_WO / EPI_OUT: float out + bias + residual
          ((float*)outp)[(size_t)m * N + n] = v + bias[n] + res[(size_t)m * N + n];
        }
      }
    }
  }
}

// ---------------- flash attention v14 (R11 proven, 92.5 us) ----------
__global__ __launch_bounds__(512) void attn_kernel(const ushort* __restrict__ Qb,
    const ushort* __restrict__ Kb, const ushort* __restrict__ Vt,
    ushort* __restrict__ ctx) {
  const int lane = threadIdx.x & 63, wave = threadIdx.x >> 6;   // 0..7
  const int col = lane & 15, quad = lane >> 4;
  const int bx = blockIdx.x;
  const int bh = bx & 63;          // XCD = bh % 8 for every q-tile of this head
  const int qt = bx >> 6;          // 0..7
  const int qbase = qt * 256 + wave * 32;
  const ushort* Qh = Qb + (size_t)bh * 2048 * 64;
  const ushort* Kh = Kb + (size_t)bh * 2048 * 64;
  const ushort* Vh = Vt + (size_t)bh * 64 * 2048;

  short8 qa[2][2];
  #pragma unroll
  for (int qg = 0; qg < 2; qg++) {
    const ushort* Qr = Qh + (size_t)(qbase + qg * 16 + col) * 64 + quad * 8;
    qa[qg][0] = *(const short8*)Qr;
    qa[qg][1] = *(const short8*)(Qr + 32);
  }

  short8 ones8;
  #pragma unroll
  for (int i = 0; i < 8; i++) ones8[i] = (short)0x3F80;   // 1.0 bf16

  f32x4 Ot[2][4], Ol[2];
  #pragma unroll
  for (int qg = 0; qg < 2; qg++) {
    Ol[qg] = (f32x4){0.f, 0.f, 0.f, 0.f};
    #pragma unroll
    for (int dt = 0; dt < 4; dt++) Ot[qg][dt] = (f32x4){0.f, 0.f, 0.f, 0.f};
  }

  __shared__ ushort Ks[2][2][64 * 32];   // [buf][d-half][key*32 + swz-chunk] 16 KB
  __shared__ ushort Vs[2][2][64 * 32];   // [buf][key-half][d*32 + swz-chunk] 16 KB
  __shared__ ushort P_lds[8][16][64];    // [wave][q][8 x 16B chunks, swz] 16 KB

  const int lrow = lane >> 2;
  const int sw = wave & 3;
  const int srow = sw * 16 + lrow;                         // row this lane stages
  const int lcol = ((lane & 3) ^ ((srow >> 1) & 3)) * 8;   // swizzled 16B chunk in 64B half
  const ushort* Kg = Kh + (size_t)srow * 64 + lcol;        // + kb*64 (+32 for half 1)
  const ushort* Vg = Vh + (size_t)srow * 2048 + lcol;      // + kb   (+32 for half 1)
  const int so = (sw * 16) * 32;
  const bool kRole = (wave < 4);

  const int kvswz = (col >> 1) & 3;   // fragment-read XOR (rows kt*16+col: (row>>1)&3)
  const int pswz = col & 7;           // P chunk XOR

  // prologue: stage chunk 0 into buf 0 (role-split)
  if (kRole) {
    async_cp16(Kg,      &Ks[0][0][so]);
    async_cp16(Kg + 32, &Ks[0][1][so]);
  } else {
    async_cp16(Vg,      &Vs[0][0][so]);
    async_cp16(Vg + 32, &Vs[0][1][so]);
  }
  __syncthreads();

  int cur = 0;
  for (int kb = 0; kb < 2048; kb += 64) {
    if (kb + 64 < 2048) {
      const int nxt = cur ^ 1;
      if (kRole) {
        async_cp16(Kg + (size_t)(kb + 64) * 64,      &Ks[nxt][0][so]);
        async_cp16(Kg + (size_t)(kb + 64) * 64 + 32, &Ks[nxt][1][so]);
      } else {
        async_cp16(Vg + (kb + 64),                   &Vs[nxt][0][so]);
        async_cp16(Vg + (kb + 64) + 32,              &Vs[nxt][1][so]);
      }
    }

    // fragments from LDS (shared across the 2 q-groups), swizzled reads
    short8 kf[4][2], vf[4][2];
    #pragma unroll
    for (int kt = 0; kt < 4; kt++)
      #pragma unroll
      for (int c = 0; c < 2; c++)
        kf[kt][c] = *(const short8*)&Ks[cur][c][(kt * 16 + col) * 32 + (quad ^ kvswz) * 8];
    #pragma unroll
    for (int dt = 0; dt < 4; dt++)
      #pragma unroll
      for (int c = 0; c < 2; c++)
        vf[dt][c] = *(const short8*)&Vs[cur][c][(dt * 16 + col) * 32 + (quad ^ kvswz) * 8];

    #pragma unroll
    for (int qg = 0; qg < 2; qg++) {
      f32x4 s[4];
      __builtin_amdgcn_s_setprio(1);
      #pragma unroll
      for (int kt = 0; kt < 4; kt++) {
        s[kt] = (f32x4){0.f, 0.f, 0.f, 0.f};
        s[kt] = MFMA_BF16(kf[kt][0], qa[qg][0], s[kt], 0, 0, 0);
        s[kt] = MFMA_BF16(kf[kt][1], qa[qg][1], s[kt], 0, 0, 0);
      }
      __builtin_amdgcn_s_setprio(0);
      ushort(*P)[64] = P_lds[wave];
      #pragma unroll
      for (int kt = 0; kt < 4; kt++) {
        float p0 = __builtin_amdgcn_exp2f(s[kt][0]);
        float p1 = __builtin_amdgcn_exp2f(s[kt][1]);
        float p2 = __builtin_amdgcn_exp2f(s[kt][2]);
        float p3 = __builtin_amdgcn_exp2f(s[kt][3]);
        uint2 pk;
        asm("v_cvt_pk_bf16_f32 %0, %1, %2" : "=v"(pk.x) : "v"(p0), "v"(p1));
        asm("v_cvt_pk_bf16_f32 %0, %1, %2" : "=v"(pk.y) : "v"(p2), "v"(p3));
        *(uint2*)&P[col][(((2 * kt + (quad >> 1)) ^ pswz) * 8) + (quad & 1) * 4] = pk;
      }
      // PV for this qg (same-wave LDS RAW handled in-order; no barrier needed)
      #pragma unroll
      for (int c = 0; c < 2; c++) {
        short8 pf = *(const short8*)&P_lds[wave][col][((4 * c + quad) ^ pswz) * 8];
        __builtin_amdgcn_s_setprio(1);
        #pragma unroll
        for (int dt = 0; dt < 4; dt++)
          Ot[qg][dt] = MFMA_BF16(vf[dt][c], pf, Ot[qg][dt], 0, 0, 0);
        Ol[qg] = MFMA_BF16(ones8, pf, Ol[qg], 0, 0, 0);   // l-sum on MFMA pipe
        __builtin_amdgcn_s_setprio(0);
      }
    }
    __syncthreads();
    cur ^= 1;
  }

  const int bb = bh >> 4, h = bh & 15;
  #pragma unroll
  for (int qg = 0; qg < 2; qg++) {
    float inv = __builtin_amdgcn_rcpf(Ol[qg][0]);   // identical in all lanes/regs
    const int q = qbase + qg * 16 + col;
    size_t base = ((size_t)(bb * 2048 + q)) * 1024 + h * 64;
    #pragma unroll
    for (int dt = 0; dt < 4; dt++) {
      ushort4 o;
      o.x = f2bf(Ot[qg][dt][0] * inv);
      o.y = f2bf(Ot[qg][dt][1] * inv);
      o.z = f2bf(Ot[qg][dt][2] * inv);
      o.w = f2bf(Ot[qg][dt][3] * inv);
      *(ushort4*)&ctx[base + dt * 16 + quad * 4] = o;
    }
  }
}

// ---------------- host ----------------
extern "C" void kernel_launch(void* const* d_in, const int* in_sizes, int n_in,
                              void* d_out, int out_size, void* d_ws, size_t ws_size,
                              hipStream_t stream) {
  const float* x     = (const float*)d_in[0];
  const float* Wq    = (const float*)d_in[1];
  const float* bq    = (const float*)d_in[2];
  const float* Wk    = (const float*)d_in[3];
  const float* bk    = (const float*)d_in[4];
  const float* Wv    = (const float*)d_in[5];
  const float* bv    = (const float*)d_in[6];
  const float* Wo    = (const float*)d_in[7];
  const float* bo    = (const float*)d_in[8];
  const float* W1    = (const float*)d_in[9];
  const float* b1    = (const float*)d_in[10];
  const float* W2    = (const float*)d_in[11];
  const float* b2    = (const float*)d_in[12];
  const float* ln1_g = (const float*)d_in[13];
  const float* ln1_b = (const float*)d_in[14];
  const float* ln2_g = (const float*)d_in[15];
  const float* ln2_b = (const float*)d_in[16];

  const size_t MB = 1ull << 20;
  char* ws = (char*)d_ws;
  ushort* Wqkv_b = (ushort*)(ws + 0 * MB);    // 6 MB  [3072,1024] (Q|K|V)
  ushort* Wo_b   = (ushort*)(ws + 6 * MB);    // 2 MB
  ushort* W1_b   = (ushort*)(ws + 8 * MB);    // 8 MB
  ushort* W2_b   = (ushort*)(ws + 16 * MB);   // 8 MB
  ushort* xn1    = (ushort*)(ws + 24 * MB);   // 16 MB
  ushort* Qb     = (ushort*)(ws + 40 * MB);   // 16 MB
  ushort* Kb     = (ushort*)(ws + 56 * MB);   // 16 MB
  ushort* Vt     = (ushort*)(ws + 72 * MB);   // 16 MB
  ushort* ctxb   = (ushort*)(ws + 88 * MB);   // 16 MB
  float*  x2     = (float*)(ws + 104 * MB);   // 32 MB
  ushort* xn2    = (ushort*)(ws + 136 * MB);  // 16 MB
  ushort* y1     = (ushort*)(ws + 152 * MB);  // 64 MB -> end 216 MB
  // bqkv aliases start of y1 (lifetime-disjoint: consumed before GELU GEMM writes y1)
  float*  bqkv   = (float*)(ws + 152 * MB);

  conv_all<<<12291, 256, 0, stream>>>(Wq, Wk, Wv, Wo, W1, W2, bq, bk, bv,
                                      Wqkv_b, Wo_b, W1_b, W2_b, bqkv);

  ln_kernel<<<8192, 256, 0, stream>>>(x, ln1_g, ln1_b, xn1);

  const float cs = 0.125f * 1.4426950408889634f;  // log2(e)/sqrt(64), folded into Q
  // Q|K projections (N=2048): 256^2 4-phase pipeline (hoisted frags, 1 barrier/phase)
  gemm256_kernel<EPI_QK><<<dim3(32, 8), 512, 0, stream>>>(
      xn1, Wqkv_b, bqkv, Qb, Kb, 1024, 2048, cs);
  // V^T projection: A = Wv (rows = v-dim, gm=8), B = xn (tokens, gn=64)
  gemmP_kernel<EPI_VT><<<512, 256, 0, stream>>>(
      Wqkv_b + (size_t)2048 * 1024, xn1, bqkv + 2048, nullptr, Vt, 1024, 8192, 64);

  attn_kernel<<<512, 512, 0, stream>>>(Qb, Kb, Vt, ctxb);

  gemmP_kernel<EPI_WO><<<512, 256, 0, stream>>>(
      ctxb, Wo_b, bo, x, x2, 1024, 1024, 8);

  ln_kernel<<<8192, 256, 0, stream>>>(x2, ln2_g, ln2_b, xn2);

  gemm256_kernel<EPI_GELU><<<dim3(32, 16), 512, 0, stream>>>(
      xn2, W1_b, b1, y1, nullptr, 1024, 4096, 1.0f);
  gemmP_kernel<EPI_OUT><<<512, 256, 0, stream>>>(
      y1, W2_b, b2, x2, d_out, 4096, 1024, 8);
}